// Round 7
// baseline (283.200 us; speedup 1.0000x reference)
//
#include <hip/hip_runtime.h>
#include <hip/hip_bf16.h>
#include <math.h>

typedef __hip_bfloat16 bf16;
typedef __attribute__((ext_vector_type(8))) short short8;   // 8 bf16 = 4 VGPRs (MFMA A/B frag)
typedef __attribute__((ext_vector_type(4))) float f32x4;    // MFMA C/D frag

static constexpr int kB = 2;
static constexpr int kT = 2048;
static constexpr int kDIM = 1024;
static constexpr int kNMETA = 4;
static constexpr int kTEXT = kT + kNMETA;   // 2052
static constexpr int kMEXT = kB * kTEXT;    // 4104
static constexpr int kMPAD = 4224;          // 33*128
static constexpr int kMX = kB * kT;         // 4096
static constexpr int kQT = 33;
static constexpr int kTP = 2112;            // 33*64

// ---------- workspace layout (bytes); ws_size ~268 MB (measured via harness poison) ----------
static constexpr size_t oXE = 0;                                  // x_ext bf16 [4224][1024]
static constexpr size_t oYB = 0;                                  // aliases XE (dead after GEMMs)
static constexpr size_t oQB = 8650752;                            // Q bf16 [4224][512]
static constexpr size_t oKB = oQB + (size_t)kMPAD * 512 * 2;      // K bf16 [4224][256]
static constexpr size_t oVB = oKB + (size_t)kMPAD * 256 * 2;      // V bf16 [4224][256]
// SSM intermediates alias QB/KB/VB after attention:
static constexpr size_t oLA = oQB;                                // la f32 [4096][128]
static constexpr size_t oUU = oLA + (size_t)kMX * 128 * 4;
static constexpr size_t oCC = oUU + (size_t)kMX * 128 * 4;
static constexpr size_t oHL = oCC + (size_t)kMX * 128 * 4;        // hloc bf16
static constexpr size_t oPB = oHL + (size_t)kMX * 128 * 2;        // P    bf16
static constexpr size_t oCH = oPB + (size_t)kMX * 128 * 2;        // chunk h  f32 [8192]
static constexpr size_t oCP = oCH + 8192 * 4;
static constexpr size_t oH0 = oCP + 8192 * 4;
static constexpr size_t oSX = oVB + (size_t)kMPAD * 256 * 2;      // ssm x bf16 [4096][512]
static constexpr size_t oQP = oSX + (size_t)kMX * 512 * 2;        // Qp bf16 [b][8][2112][64]
static constexpr size_t oKP = oQP + (size_t)kB * 8 * kTP * 64 * 2;// Kp bf16 [b][4][2112][64]
static constexpr size_t oVT = oKP + (size_t)kB * 4 * kTP * 64 * 2;// Vt bf16 [b][4][64][2112]
static constexpr size_t oWQ = oQP;                                // WQKV+WSX bf16 [1536][1024] (early; dead before norm_rope_pack)
static constexpr size_t oWP = oVT + (size_t)kB * 4 * 64 * kTP * 2;// Wproj bf16 [1024][1024] (own region, live to the end)

#define GLD_LDS16(gp, lp)                                                          \
  __builtin_amdgcn_global_load_lds((const __attribute__((address_space(1))) void*)(gp), \
                                   (__attribute__((address_space(3))) void*)(lp), 16, 0, 0)

__device__ __forceinline__ uint4 pack8(float4 a, float4 b) {
  union { bf16 h[8]; uint4 v; } u;
  u.h[0] = __float2bfloat16(a.x); u.h[1] = __float2bfloat16(a.y);
  u.h[2] = __float2bfloat16(a.z); u.h[3] = __float2bfloat16(a.w);
  u.h[4] = __float2bfloat16(b.x); u.h[5] = __float2bfloat16(b.y);
  u.h[6] = __float2bfloat16(b.z); u.h[7] = __float2bfloat16(b.w);
  return u.v;
}

// ---------------- all weight converts + x_ext build in one launch ----------------
__global__ __launch_bounds__(256) void prep_all(const float* __restrict__ cq, const float* __restrict__ ck,
                                                const float* __restrict__ cv, const float* __restrict__ sw,
                                                const float* __restrict__ pw,
                                                const float* __restrict__ x, const float* __restrict__ meta,
                                                bf16* __restrict__ wqkvsx, bf16* __restrict__ wproj,
                                                bf16* __restrict__ xe) {
  int i = blockIdx.x * 256 + threadIdx.x;
  int row = i >> 7, v = i & 127;
  if (row < 2560) {
    const float* src; bf16* dst;
    if (row < 512)       { src = cq + (size_t)row * 1024;          dst = wqkvsx + (size_t)row * 1024; }
    else if (row < 768)  { src = ck + (size_t)(row - 512) * 1024;  dst = wqkvsx + (size_t)row * 1024; }
    else if (row < 1024) { src = cv + (size_t)(row - 768) * 1024;  dst = wqkvsx + (size_t)row * 1024; }
    else if (row < 1536) { src = sw + (size_t)(row - 1024) * 1024; dst = wqkvsx + (size_t)row * 1024; }
    else                 { src = pw + (size_t)(row - 1536) * 1024; dst = wproj + (size_t)(row - 1536) * 1024; }
    float4 a0 = ((const float4*)src)[v * 2], a1 = ((const float4*)src)[v * 2 + 1];
    ((uint4*)dst)[v] = pack8(a0, a1);
  } else {
    int r = row - 2560;
    if (r >= kMPAD) return;
    uint4 val = {0u, 0u, 0u, 0u};
    if (r < kMEXT) {
      int b = r / kTEXT, te = r - b * kTEXT;
      const float* src = (te < kNMETA) ? (meta + (size_t)te * kDIM)
                                       : (x + ((size_t)b * kT + (te - kNMETA)) * kDIM);
      float4 a0 = ((const float4*)src)[v * 2];
      float4 a1 = ((const float4*)src)[v * 2 + 1];
      val = pack8(a0, a1);
    }
    ((uint4*)(xe + (size_t)r * kDIM))[v] = val;
  }
}

// ================= 128x128-tile bf16 GEMM, m97 structure (K=1024, BK=32) =================
// MODE 0: fused QKV+SX (N=1536; epilogue scatter). MODE 2: proj (N=1024, f32 out).
template <int MODE>
__global__ __launch_bounds__(256) void gemm128(const bf16* __restrict__ A,
                                               const bf16* __restrict__ W,
                                               void* __restrict__ O0, void* __restrict__ O1,
                                               void* __restrict__ O2, void* __restrict__ O3) {
  __shared__ short As[128 * 32];
  __shared__ short Bs[128 * 32];
  const int tid = threadIdx.x;
  const int wave = tid >> 6, lane = tid & 63;
  const int wr = wave >> 1, wc = wave & 1;
  const int quad = lane >> 4, l16 = lane & 15;
  const int bm = blockIdx.y * 128, bn = blockIdx.x * 128;
  const int srow = tid >> 2, scol = (tid & 3) * 8;
  const bf16* ag0 = A + (size_t)(bm + srow) * 1024 + scol;
  const bf16* ag1 = A + (size_t)(bm + 64 + srow) * 1024 + scol;
  const bf16* bg0 = W + (size_t)(bn + srow) * 1024 + scol;
  const bf16* bg1 = W + (size_t)(bn + 64 + srow) * 1024 + scol;
  char* asb = (char*)As + wave * 1024;
  char* bsb = (char*)Bs + wave * 1024;
  f32x4 acc[4][4] = {};
  for (int k0 = 0; k0 < 1024; k0 += 32) {
    __syncthreads();
    GLD_LDS16(ag0, asb);
    GLD_LDS16(ag1, asb + 4096);
    GLD_LDS16(bg0, bsb);
    GLD_LDS16(bg1, bsb + 4096);
    ag0 += 32; ag1 += 32; bg0 += 32; bg1 += 32;
    __syncthreads();
    short8 af[4], bfr[4];
#pragma unroll
    for (int mi = 0; mi < 4; ++mi)
      af[mi] = *(const short8*)((const char*)As + (size_t)(wr * 64 + mi * 16 + l16) * 64 + quad * 16);
#pragma unroll
    for (int ni = 0; ni < 4; ++ni)
      bfr[ni] = *(const short8*)((const char*)Bs + (size_t)(wc * 64 + ni * 16 + l16) * 64 + quad * 16);
#pragma unroll
    for (int mi = 0; mi < 4; ++mi)
#pragma unroll
      for (int ni = 0; ni < 4; ++ni)
        acc[mi][ni] = __builtin_amdgcn_mfma_f32_16x16x32_bf16(af[mi], bfr[ni], acc[mi][ni], 0, 0, 0);
  }
#pragma unroll
  for (int mi = 0; mi < 4; ++mi)
#pragma unroll
    for (int ni = 0; ni < 4; ++ni) {
      int colg = bn + wc * 64 + ni * 16 + l16;
#pragma unroll
      for (int r = 0; r < 4; ++r) {
        int row = bm + wr * 64 + mi * 16 + quad * 4 + r;
        float val = acc[mi][ni][r];
        if constexpr (MODE == 2) {
          ((float*)O0)[(size_t)row * 1024 + colg] = val;
        } else {
          if (colg < 512)       ((bf16*)O0)[(size_t)row * 512 + colg]        = __float2bfloat16(val);
          else if (colg < 768)  ((bf16*)O1)[(size_t)row * 256 + colg - 512]  = __float2bfloat16(val);
          else if (colg < 1024) ((bf16*)O2)[(size_t)row * 256 + colg - 768]  = __float2bfloat16(val);
          else if (row < kMEXT) {
            int bb = row >= kTEXT ? 1 : 0;
            int te = row - bb * kTEXT;
            if (te >= kNMETA)
              ((bf16*)O3)[((size_t)(bb * kT + te - kNMETA)) * 512 + colg - 1024] = __float2bfloat16(val);
          }
        }
      }
    }
}

// ------- RMSnorm + RoPE (+q_gain, +1/sqrt(D)) -> packed Qp[b][8][2112][64], Kp[b][4][2112][64]
__global__ __launch_bounds__(256) void norm_rope_pack(const bf16* __restrict__ QB,
                                                      const bf16* __restrict__ KB,
                                                      const float* __restrict__ q_gain,
                                                      bf16* __restrict__ Qp, bf16* __restrict__ Kp) {
  int job = blockIdx.x * 4 + (threadIdx.x >> 6);
  if (job >= kB * kTP * 12) return;
  int lane = threadIdx.x & 63;
  int slot = job % 12, rowp = job / 12;
  int b = rowp / kTP, te = rowp % kTP;
  bf16* dst = (slot < 8) ? Qp + (((size_t)(b * 8 + slot)) * kTP + te) * 64 + lane
                         : Kp + (((size_t)(b * 4 + slot - 8)) * kTP + te) * 64 + lane;
  if (te >= kTEXT) { *dst = __float2bfloat16(0.f); return; }
  const bf16* src = (slot < 8) ? QB + ((size_t)(b * kTEXT + te)) * 512 + slot * 64 + lane
                               : KB + ((size_t)(b * kTEXT + te)) * 256 + (slot - 8) * 64 + lane;
  float v = __bfloat162float(*src);
  float ss = v * v;
#pragma unroll
  for (int o = 32; o > 0; o >>= 1) ss += __shfl_xor(ss, o, 64);
  float vn = v * (1.f / sqrtf(ss * (1.f / 64.f) + 1e-6f));
  float p = __shfl_xor(vn, 32, 64);
  float ang = (float)te * exp2f(-13.287712379549449f * (float)(lane & 31) * (1.f / 32.f));
  float c = __cosf(ang), s = __sinf(ang);
  float outv = (lane < 32) ? (vn * c - p * s) : (p * s + vn * c);
  float gain = (slot < 8) ? q_gain[slot] * 0.125f : 1.f;
  *dst = __float2bfloat16(outv * gain);
}

// ------- V transpose: VB[row][256] -> Vt[b][kvh][64][2112] (zero pads), LDS-tiled -------
__global__ __launch_bounds__(256) void vrepack(const bf16* __restrict__ VB, bf16* __restrict__ Vt) {
  __shared__ short Ts[64][66];
  const int tt = blockIdx.x, kvh = blockIdx.y, b = blockIdx.z;
  const int tid = threadIdx.x;
#pragma unroll
  for (int r = 0; r < 2; ++r) {
    int e = r * 256 + tid, row = e >> 3, c8 = e & 7;
    int te = tt * 64 + row;
    uint4 val = {0u, 0u, 0u, 0u};
    if (te < kTEXT) val = *(const uint4*)(VB + ((size_t)(b * kTEXT + te)) * 256 + kvh * 64 + c8 * 8);
    union { uint4 u; short s[8]; } w; w.u = val;
#pragma unroll
    for (int i = 0; i < 8; ++i) Ts[row][c8 * 8 + i] = w.s[i];
  }
  __syncthreads();
#pragma unroll
  for (int r = 0; r < 2; ++r) {
    int e = r * 256 + tid, d = e >> 3, c8 = e & 7;
    union { uint4 u; short s[8]; } w;
#pragma unroll
    for (int i = 0; i < 8; ++i) w.s[i] = Ts[c8 * 8 + i][d];
    *(uint4*)(Vt + (((size_t)(b * 4 + kvh)) * 64 + d) * kTP + tt * 64 + c8 * 8) = w.u;
  }
}

// ---------------- MFMA causal flash attention: 2 heads / block (shared K/V) ----------------
__global__ __launch_bounds__(256) void attn_mfma(const bf16* __restrict__ Qp,
                                                 const bf16* __restrict__ Kp,
                                                 const bf16* __restrict__ Vt,
                                                 const float* __restrict__ attn_scale,
                                                 bf16* __restrict__ Y) {
  __shared__ short Ks[64][72];        // K tile [key][d]
  __shared__ short Vs[64][72];        // V^T tile [d][key]
  __shared__ short Ps[4][16][72];     // per-wave P [q][key]
  const int qt = (kQT - 1) - blockIdx.x;   // longest first
  const int kvh = blockIdx.y, b = blockIdx.z;
  const int h0 = kvh * 2;
  const int tid = threadIdx.x, wave = tid >> 6, lane = tid & 63;
  const int quad = lane >> 4, l16 = lane & 15;

  short8 qf[2][2];
#pragma unroll
  for (int hh = 0; hh < 2; ++hh) {
    const bf16* qrow = Qp + (((size_t)(b * 8 + h0 + hh)) * kTP + qt * 64 + wave * 16 + l16) * 64 + quad * 8;
    qf[hh][0] = *(const short8*)(qrow);
    qf[hh][1] = *(const short8*)(qrow + 32);
  }
  short8 ones;
#pragma unroll
  for (int i = 0; i < 8; ++i) ones[i] = (short)0x3F80;   // bf16 1.0

  const bf16* kbase = Kp + ((size_t)(b * 4 + kvh)) * kTP * 64;
  const bf16* vbase = Vt + ((size_t)(b * 4 + kvh)) * 64 * kTP;

  f32x4 O[2][4] = {};
  f32x4 lacc[2] = {};
  const int q_abs = qt * 64 + wave * 16 + l16;

  for (int kt = 0; kt <= qt; ++kt) {
    __syncthreads();
#pragma unroll
    for (int r = 0; r < 2; ++r) {
      int e = r * 256 + tid, row = e >> 3, c8 = e & 7;
      uint4 kv = *(const uint4*)(kbase + ((size_t)(kt * 64 + row)) * 64 + c8 * 8);
      *(uint4*)&Ks[row][c8 * 8] = kv;
      uint4 vv = *(const uint4*)(vbase + (size_t)row * kTP + kt * 64 + c8 * 8);
      *(uint4*)&Vs[row][c8 * 8] = vv;
    }
    __syncthreads();

    // ---- S^T = K * Q^T for both heads; K-fragments read once ----
    f32x4 st[2][4] = {};
#pragma unroll
    for (int nb = 0; nb < 4; ++nb) {
      short8 ak0 = *(const short8*)&Ks[nb * 16 + l16][quad * 8];
      short8 ak1 = *(const short8*)&Ks[nb * 16 + l16][32 + quad * 8];
#pragma unroll
      for (int hh = 0; hh < 2; ++hh) {
        st[hh][nb] = __builtin_amdgcn_mfma_f32_16x16x32_bf16(ak0, qf[hh][0], st[hh][nb], 0, 0, 0);
        st[hh][nb] = __builtin_amdgcn_mfma_f32_16x16x32_bf16(ak1, qf[hh][1], st[hh][nb], 0, 0, 0);
      }
    }
    if (kt == qt) {
      int key0 = kt * 64 + quad * 4;
#pragma unroll
      for (int nb = 0; nb < 4; ++nb)
#pragma unroll
        for (int rg = 0; rg < 4; ++rg)
          if (key0 + nb * 16 + rg > q_abs) { st[0][nb][rg] = -1e30f; st[1][nb][rg] = -1e30f; }
    }
#pragma unroll
    for (int hh = 0; hh < 2; ++hh) {
#pragma unroll
      for (int nb = 0; nb < 4; ++nb) {
        union { unsigned long long q; bf16 hhv[4]; } pw;
#pragma unroll
        for (int rg = 0; rg < 4; ++rg) pw.hhv[rg] = __float2bfloat16(__expf(st[hh][nb][rg]));
        *(unsigned long long*)&Ps[wave][l16][nb * 16 + quad * 4] = pw.q;
      }
      short8 pf0 = *(const short8*)&Ps[wave][l16][quad * 8];
      short8 pf1 = *(const short8*)&Ps[wave][l16][32 + quad * 8];
      lacc[hh] = __builtin_amdgcn_mfma_f32_16x16x32_bf16(pf0, ones, lacc[hh], 0, 0, 0);
      lacc[hh] = __builtin_amdgcn_mfma_f32_16x16x32_bf16(pf1, ones, lacc[hh], 0, 0, 0);
#pragma unroll
      for (int db = 0; db < 4; ++db) {
        short8 bv0 = *(const short8*)&Vs[db * 16 + l16][quad * 8];
        O[hh][db] = __builtin_amdgcn_mfma_f32_16x16x32_bf16(pf0, bv0, O[hh][db], 0, 0, 0);
        short8 bv1 = *(const short8*)&Vs[db * 16 + l16][32 + quad * 8];
        O[hh][db] = __builtin_amdgcn_mfma_f32_16x16x32_bf16(pf1, bv1, O[hh][db], 0, 0, 0);
      }
    }
  }
  float asc = attn_scale[0];
#pragma unroll
  for (int hh = 0; hh < 2; ++hh)
#pragma unroll
    for (int rg = 0; rg < 4; ++rg) {
      int te_q = qt * 64 + wave * 16 + quad * 4 + rg;
      if (te_q < kNMETA || te_q >= kTEXT) continue;
      float so = asc / fmaxf(lacc[hh][rg], 1e-30f);
      bf16* dst = Y + ((size_t)(b * kT + te_q - kNMETA)) * kDIM + (h0 + hh) * 64 + l16;
#pragma unroll
      for (int db = 0; db < 4; ++db) dst[db * 16] = __float2bfloat16(O[hh][db][rg] * so);
    }
}

// ---------------- SSM prep via MFMA: per head h, [64 bt rows] x [48 = dt|B|C] ----------------
__global__ __launch_bounds__(256) void ssm_prep(const bf16* __restrict__ sx,
                                                const float* __restrict__ dtw, const float* __restrict__ dtb,
                                                const float* __restrict__ Bw, const float* __restrict__ Cw,
                                                const float* __restrict__ logA,
                                                float* __restrict__ la, float* __restrict__ u,
                                                float* __restrict__ Cc) {
  __shared__ short Xs[64][72];
  __shared__ short Ws[48][72];
  const int bm = blockIdx.x * 64, h = blockIdx.y;
  const int tid = threadIdx.x, wave = tid >> 6, lane = tid & 63;
  const int quad = lane >> 4, l16 = lane & 15;
#pragma unroll
  for (int is = 0; is < 2; ++is) {
    int e = is * 256 + tid;
    int row = e >> 3, v = e & 7;
    uint4 val = *(const uint4*)(sx + ((size_t)(bm + row)) * 512 + h * 64 + v * 8);
    *(uint4*)&Xs[row][v * 8] = val;
  }
#pragma unroll
  for (int is = 0; is < 2; ++is) {
    int s = is * 256 + tid;
    if (s < 384) {
      int row = s >> 3, v = s & 7;
      const float* src = (row < 16) ? dtw + ((size_t)(h * 16 + row)) * 64
                       : (row < 32) ? Bw + ((size_t)(h * 16 + row - 16)) * 64
                                    : Cw + ((size_t)(h * 16 + row - 32)) * 64;
      float4 a0 = ((const float4*)src)[v * 2];
      float4 a1 = ((const float4*)src)[v * 2 + 1];
      *(uint4*)&Ws[row][v * 8] = pack8(a0, a1);
    }
  }
  __syncthreads();
  short8 af0 = *(const short8*)&Xs[wave * 16 + l16][quad * 8];
  short8 af1 = *(const short8*)&Xs[wave * 16 + l16][32 + quad * 8];
  f32x4 acc[3] = {};
#pragma unroll
  for (int nb = 0; nb < 3; ++nb) {
    short8 b0 = *(const short8*)&Ws[nb * 16 + l16][quad * 8];
    acc[nb] = __builtin_amdgcn_mfma_f32_16x16x32_bf16(af0, b0, acc[nb], 0, 0, 0);
    short8 b1 = *(const short8*)&Ws[nb * 16 + l16][32 + quad * 8];
    acc[nb] = __builtin_amdgcn_mfma_f32_16x16x32_bf16(af1, b1, acc[nb], 0, 0, 0);
  }
  float dtb_v = dtb[h * 16 + l16];
  float A_v = fminf(-expf(logA[h * 16 + l16]), 10.f);
#pragma unroll
  for (int rg = 0; rg < 4; ++rg) {
    int bt = bm + wave * 16 + quad * 4 + rg;
    size_t ix = (size_t)bt * 128 + h * 16 + l16;
    float raw = acc[0][rg] + dtb_v;
    float sp = fmaxf(raw, 0.f) + log1pf(expf(-fabsf(raw)));   // stable softplus
    float dt = fminf(sp, 1.f);
    float lav = fminf(fmaxf(dt * A_v, -0.5f), 0.f);
    la[ix] = lav;
    u[ix] = acc[1][rg] * dt;
    Cc[ix] = acc[2][rg];
  }
}

__global__ __launch_bounds__(256) void ssm_scan1(const float* __restrict__ la, const float* __restrict__ u,
                                                 bf16* __restrict__ hloc, bf16* __restrict__ Pb,
                                                 float* __restrict__ chH, float* __restrict__ chP) {
  int id = blockIdx.x * 256 + threadIdx.x;
  if (id >= 8192) return;
  int hs = id & 127, c = (id >> 7) & 31, b = id >> 12;
  float hv = 0.f, cum = 0.f;
  size_t base = ((size_t)b * kT) * 128 + hs;
  for (int i = 0; i < 64; ++i) {
    size_t ix = base + (size_t)(c * 64 + i) * 128;
    float lav = la[ix], uv = u[ix];
    cum += lav;
    hv = expf(lav) * hv + uv;
    hloc[ix] = __float2bfloat16(hv);
    Pb[ix] = __float2bfloat16(expf(fmaxf(cum, -30.f)));
  }
  chH[id] = hv;
  chP[id] = expf(fmaxf(cum, -30.f));
}

__global__ __launch_bounds__(256) void ssm_scan2(const float* __restrict__ chH,
                                                 const float* __restrict__ chP,
                                                 float* __restrict__ h0) {
  int id = threadIdx.x;
  int b = id >> 7, hs = id & 127;
  float h0v = 0.f;
  for (int c = 0; c < 32; ++c) {
    int ci = b * 4096 + c * 128 + hs;
    h0[ci] = h0v;
    h0v = chH[ci] + chP[ci] * h0v;
  }
}

// h = hloc + P*h0 ; y = sum Cc*h ; out = h@Ow^T + y*x0 ; 4 threads per (b,t,h), 16 d each
__global__ __launch_bounds__(256) void ssm_out(const bf16* __restrict__ hloc, const bf16* __restrict__ Pb,
                                               const float* __restrict__ h0, const float* __restrict__ Cc,
                                               const bf16* __restrict__ sx, const float* __restrict__ Ow,
                                               const float* __restrict__ ssm_scale, bf16* __restrict__ Y) {
  int id = blockIdx.x * 256 + threadIdx.x;   // kMX*8*4
  if (id >= kMX * 32) return;
  int d4 = id & 3, h = (id >> 2) & 7, t = (id >> 5) & 2047, b = id >> 16;
  size_t ix0 = ((size_t)(b * kT + t)) * 128 + h * 16;
  int h0b = b * 4096 + (t >> 6) * 128 + h * 16;
  float hv[16], y = 0.f;
#pragma unroll
  for (int s = 0; s < 16; ++s) {
    float v = __bfloat162float(hloc[ix0 + s]) + __bfloat162float(Pb[ix0 + s]) * h0[h0b + s];
    hv[s] = v;
    y += Cc[ix0 + s] * v;
  }
  float x0 = __bfloat162float(sx[((size_t)(b * kT + t)) * 512 + h * 64]);
  float scl = ssm_scale[0];
  const float* ow = Ow + ((size_t)h * 64 + d4 * 16) * 16;
  bf16* dst = Y + ((size_t)(b * kT + t)) * kDIM + 512 + h * 64 + d4 * 16;
  float yx = y * x0;
#pragma unroll
  for (int d = 0; d < 16; ++d) {
    float acc = yx;
    const float* owr = ow + d * 16;
#pragma unroll
    for (int s = 0; s < 16; ++s) acc += hv[s] * owr[s];
    dst[d] = __float2bfloat16(acc * scl);
  }
}

// ---------------- host ----------------
extern "C" void kernel_launch(void* const* d_in, const int* in_sizes, int n_in,
                              void* d_out, int out_size, void* d_ws, size_t ws_size,
                              hipStream_t stream) {
  (void)in_sizes; (void)n_in; (void)out_size; (void)ws_size;
  const float* x        = (const float*)d_in[0];
  const float* meta     = (const float*)d_in[1];
  const float* c_q_w    = (const float*)d_in[2];
  const float* c_k_w    = (const float*)d_in[3];
  const float* c_v_w    = (const float*)d_in[4];
  const float* q_gain   = (const float*)d_in[5];
  const float* ssm_in_w = (const float*)d_in[6];
  const float* proj_w   = (const float*)d_in[7];
  const float* attn_sc  = (const float*)d_in[8];
  const float* ssm_sc   = (const float*)d_in[9];
  const float* ssm_logA = (const float*)d_in[10];
  const float* ssm_Bw   = (const float*)d_in[11];
  const float* ssm_Cw   = (const float*)d_in[12];
  const float* ssm_dtw  = (const float*)d_in[13];
  const float* ssm_dtb  = (const float*)d_in[14];
  const float* ssm_Ow   = (const float*)d_in[15];

  char* w = (char*)d_ws;
  bf16*  XE = (bf16*)(w + oXE);
  bf16*  QB = (bf16*)(w + oQB);
  bf16*  KB = (bf16*)(w + oKB);
  bf16*  VB = (bf16*)(w + oVB);
  bf16*  SX = (bf16*)(w + oSX);
  bf16*  YB = (bf16*)(w + oYB);
  bf16*  QP = (bf16*)(w + oQP);
  bf16*  KP = (bf16*)(w + oKP);
  bf16*  VT = (bf16*)(w + oVT);
  bf16*  WQ = (bf16*)(w + oWQ);
  bf16*  WP = (bf16*)(w + oWP);
  float* LA = (float*)(w + oLA);
  float* UU = (float*)(w + oUU);
  float* CC = (float*)(w + oCC);
  bf16*  HL = (bf16*)(w + oHL);
  bf16*  PB = (bf16*)(w + oPB);
  float* CH = (float*)(w + oCH);
  float* CP = (float*)(w + oCP);
  float* H0 = (float*)(w + oH0);

  prep_all<<<(2560 + kMPAD) * 128 / 256, 256, 0, stream>>>(c_q_w, c_k_w, c_v_w, ssm_in_w, proj_w,
                                                           x, meta, WQ, WP, XE);

  gemm128<0><<<dim3(12, kMPAD / 128), 256, 0, stream>>>(XE, WQ, QB, KB, VB, SX);   // QKV+SX fused

  norm_rope_pack<<<(kB * kTP * 12) / 4, 256, 0, stream>>>(QB, KB, q_gain, QP, KP);
  vrepack<<<dim3(kQT, 4, kB), 256, 0, stream>>>(VB, VT);

  attn_mfma<<<dim3(kQT, 4, kB), 256, 0, stream>>>(QP, KP, VT, attn_sc, YB);

  ssm_prep<<<dim3(kMX / 64, 8), 256, 0, stream>>>(SX, ssm_dtw, ssm_dtb, ssm_Bw, ssm_Cw,
                                                  ssm_logA, LA, UU, CC);
  ssm_scan1<<<32, 256, 0, stream>>>(LA, UU, HL, PB, CH, CP);
  ssm_scan2<<<1, 256, 0, stream>>>(CH, CP, H0);
  ssm_out<<<kMX * 32 / 256, 256, 0, stream>>>(HL, PB, H0, CC, SX, ssm_Ow, ssm_sc, YB);

  gemm128<2><<<dim3(8, kMX / 128), 256, 0, stream>>>(YB, WP, d_out, nullptr, nullptr, nullptr);
}

// Round 8
// 243.079 us; speedup vs baseline: 1.1651x; 1.1651x over previous
//
#include <hip/hip_runtime.h>
#include <hip/hip_bf16.h>
#include <math.h>

typedef __hip_bfloat16 bf16;
typedef __attribute__((ext_vector_type(8))) short short8;   // 8 bf16 = 4 VGPRs (MFMA A/B frag)
typedef __attribute__((ext_vector_type(4))) float f32x4;    // MFMA C/D frag

static constexpr int kB = 2;
static constexpr int kT = 2048;
static constexpr int kDIM = 1024;
static constexpr int kNMETA = 4;
static constexpr int kTEXT = kT + kNMETA;   // 2052
static constexpr int kMEXT = kB * kTEXT;    // 4104
static constexpr int kMPAD = 4224;          // 33*128
static constexpr int kMX = kB * kT;         // 4096
static constexpr int kQT = 33;
static constexpr int kTP = 2112;            // 33*64

// ---------- workspace layout (bytes); ws ~268 MB ----------
static constexpr size_t oXE = 0;                                  // x_ext bf16 [4224][1024]
static constexpr size_t oYB = 0;                                  // aliases XE (dead after GEMMs)
static constexpr size_t oQB = 8650752;                            // Q bf16 [4224][512]
static constexpr size_t oKB = oQB + (size_t)kMPAD * 512 * 2;      // K bf16 [4224][256]
static constexpr size_t oVB = oKB + (size_t)kMPAD * 256 * 2;      // V bf16 [4224][256]
// SSM intermediates alias QB/KB/VB after attention:
static constexpr size_t oLA = oQB;                                // la f32 [4096][128]
static constexpr size_t oUU = oLA + (size_t)kMX * 128 * 4;
static constexpr size_t oCC = oUU + (size_t)kMX * 128 * 4;
static constexpr size_t oHL = oCC + (size_t)kMX * 128 * 4;        // hloc bf16
static constexpr size_t oPB = oHL + (size_t)kMX * 128 * 2;        // P    bf16
static constexpr size_t oCH = oPB + (size_t)kMX * 128 * 2;        // chunk h  f32 [8192]
static constexpr size_t oCP = oCH + 8192 * 4;
static constexpr size_t oH0 = oCP + 8192 * 4;
static constexpr size_t oSX = oVB + (size_t)kMPAD * 256 * 2;      // ssm x bf16 [4096][512]
static constexpr size_t oQP = oSX + (size_t)kMX * 512 * 2;        // Qp bf16 [b][8][2112][64]
static constexpr size_t oKP = oQP + (size_t)kB * 8 * kTP * 64 * 2;// Kp bf16 [b][4][2112][64]
static constexpr size_t oVT = oKP + (size_t)kB * 4 * kTP * 64 * 2;// Vt bf16 [b][4][64][2112]
static constexpr size_t oWQ = oQP;                                // WQKV+WSX bf16 [1536][1024] (early)
static constexpr size_t oWP = oVT + (size_t)kB * 4 * 64 * kTP * 2;// Wproj bf16 [1024][1024]

#define GLD_LDS16(gp, lp)                                                          \
  __builtin_amdgcn_global_load_lds((const __attribute__((address_space(1))) void*)(gp), \
                                   (__attribute__((address_space(3))) void*)(lp), 16, 0, 0)

__device__ __forceinline__ uint4 pack8(float4 a, float4 b) {
  union { bf16 h[8]; uint4 v; } u;
  u.h[0] = __float2bfloat16(a.x); u.h[1] = __float2bfloat16(a.y);
  u.h[2] = __float2bfloat16(a.z); u.h[3] = __float2bfloat16(a.w);
  u.h[4] = __float2bfloat16(b.x); u.h[5] = __float2bfloat16(b.y);
  u.h[6] = __float2bfloat16(b.z); u.h[7] = __float2bfloat16(b.w);
  return u.v;
}

// ---------------- all weight converts + x_ext build in one launch ----------------
__global__ __launch_bounds__(256) void prep_all(const float* __restrict__ cq, const float* __restrict__ ck,
                                                const float* __restrict__ cv, const float* __restrict__ sw,
                                                const float* __restrict__ pw,
                                                const float* __restrict__ x, const float* __restrict__ meta,
                                                bf16* __restrict__ wqkvsx, bf16* __restrict__ wproj,
                                                bf16* __restrict__ xe) {
  int i = blockIdx.x * 256 + threadIdx.x;
  int row = i >> 7, v = i & 127;
  if (row < 2560) {
    const float* src; bf16* dst;
    if (row < 512)       { src = cq + (size_t)row * 1024;          dst = wqkvsx + (size_t)row * 1024; }
    else if (row < 768)  { src = ck + (size_t)(row - 512) * 1024;  dst = wqkvsx + (size_t)row * 1024; }
    else if (row < 1024) { src = cv + (size_t)(row - 768) * 1024;  dst = wqkvsx + (size_t)row * 1024; }
    else if (row < 1536) { src = sw + (size_t)(row - 1024) * 1024; dst = wqkvsx + (size_t)row * 1024; }
    else                 { src = pw + (size_t)(row - 1536) * 1024; dst = wproj + (size_t)(row - 1536) * 1024; }
    float4 a0 = ((const float4*)src)[v * 2], a1 = ((const float4*)src)[v * 2 + 1];
    ((uint4*)dst)[v] = pack8(a0, a1);
  } else {
    int r = row - 2560;
    if (r >= kMPAD) return;
    uint4 val = {0u, 0u, 0u, 0u};
    if (r < kMEXT) {
      int b = r / kTEXT, te = r - b * kTEXT;
      const float* src = (te < kNMETA) ? (meta + (size_t)te * kDIM)
                                       : (x + ((size_t)b * kT + (te - kNMETA)) * kDIM);
      float4 a0 = ((const float4*)src)[v * 2];
      float4 a1 = ((const float4*)src)[v * 2 + 1];
      val = pack8(a0, a1);
    }
    ((uint4*)(xe + (size_t)r * kDIM))[v] = val;
  }
}

// ================= 128x128-tile bf16 GEMM, m97 structure (K=1024, BK=32) =================
template <int MODE>
__global__ __launch_bounds__(256) void gemm128(const bf16* __restrict__ A,
                                               const bf16* __restrict__ W,
                                               void* __restrict__ O0, void* __restrict__ O1,
                                               void* __restrict__ O2, void* __restrict__ O3) {
  __shared__ short As[128 * 32];
  __shared__ short Bs[128 * 32];
  const int tid = threadIdx.x;
  const int wave = tid >> 6, lane = tid & 63;
  const int wr = wave >> 1, wc = wave & 1;
  const int quad = lane >> 4, l16 = lane & 15;
  const int bm = blockIdx.y * 128, bn = blockIdx.x * 128;
  const int srow = tid >> 2, scol = (tid & 3) * 8;
  const bf16* ag0 = A + (size_t)(bm + srow) * 1024 + scol;
  const bf16* ag1 = A + (size_t)(bm + 64 + srow) * 1024 + scol;
  const bf16* bg0 = W + (size_t)(bn + srow) * 1024 + scol;
  const bf16* bg1 = W + (size_t)(bn + 64 + srow) * 1024 + scol;
  char* asb = (char*)As + wave * 1024;
  char* bsb = (char*)Bs + wave * 1024;
  f32x4 acc[4][4] = {};
  for (int k0 = 0; k0 < 1024; k0 += 32) {
    __syncthreads();
    GLD_LDS16(ag0, asb);
    GLD_LDS16(ag1, asb + 4096);
    GLD_LDS16(bg0, bsb);
    GLD_LDS16(bg1, bsb + 4096);
    ag0 += 32; ag1 += 32; bg0 += 32; bg1 += 32;
    __syncthreads();
    short8 af[4], bfr[4];
#pragma unroll
    for (int mi = 0; mi < 4; ++mi)
      af[mi] = *(const short8*)((const char*)As + (size_t)(wr * 64 + mi * 16 + l16) * 64 + quad * 16);
#pragma unroll
    for (int ni = 0; ni < 4; ++ni)
      bfr[ni] = *(const short8*)((const char*)Bs + (size_t)(wc * 64 + ni * 16 + l16) * 64 + quad * 16);
#pragma unroll
    for (int mi = 0; mi < 4; ++mi)
#pragma unroll
      for (int ni = 0; ni < 4; ++ni)
        acc[mi][ni] = __builtin_amdgcn_mfma_f32_16x16x32_bf16(af[mi], bfr[ni], acc[mi][ni], 0, 0, 0);
  }
#pragma unroll
  for (int mi = 0; mi < 4; ++mi)
#pragma unroll
    for (int ni = 0; ni < 4; ++ni) {
      int colg = bn + wc * 64 + ni * 16 + l16;
#pragma unroll
      for (int r = 0; r < 4; ++r) {
        int row = bm + wr * 64 + mi * 16 + quad * 4 + r;
        float val = acc[mi][ni][r];
        if constexpr (MODE == 2) {
          ((float*)O0)[(size_t)row * 1024 + colg] = val;
        } else {
          if (colg < 512)       ((bf16*)O0)[(size_t)row * 512 + colg]        = __float2bfloat16(val);
          else if (colg < 768)  ((bf16*)O1)[(size_t)row * 256 + colg - 512]  = __float2bfloat16(val);
          else if (colg < 1024) ((bf16*)O2)[(size_t)row * 256 + colg - 768]  = __float2bfloat16(val);
          else if (row < kMEXT) {
            int bb = row >= kTEXT ? 1 : 0;
            int te = row - bb * kTEXT;
            if (te >= kNMETA)
              ((bf16*)O3)[((size_t)(bb * kT + te - kNMETA)) * 512 + colg - 1024] = __float2bfloat16(val);
          }
        }
      }
    }
}

// ------- RMSnorm + RoPE (+q_gain, +1/sqrt(D)) -> packed Qp[b][8][2112][64], Kp[b][4][2112][64]
__global__ __launch_bounds__(256) void norm_rope_pack(const bf16* __restrict__ QB,
                                                      const bf16* __restrict__ KB,
                                                      const float* __restrict__ q_gain,
                                                      bf16* __restrict__ Qp, bf16* __restrict__ Kp) {
  int job = blockIdx.x * 4 + (threadIdx.x >> 6);
  if (job >= kB * kTP * 12) return;
  int lane = threadIdx.x & 63;
  int slot = job % 12, rowp = job / 12;
  int b = rowp / kTP, te = rowp % kTP;
  bf16* dst = (slot < 8) ? Qp + (((size_t)(b * 8 + slot)) * kTP + te) * 64 + lane
                         : Kp + (((size_t)(b * 4 + slot - 8)) * kTP + te) * 64 + lane;
  if (te >= kTEXT) { *dst = __float2bfloat16(0.f); return; }
  const bf16* src = (slot < 8) ? QB + ((size_t)(b * kTEXT + te)) * 512 + slot * 64 + lane
                               : KB + ((size_t)(b * kTEXT + te)) * 256 + (slot - 8) * 64 + lane;
  float v = __bfloat162float(*src);
  float ss = v * v;
#pragma unroll
  for (int o = 32; o > 0; o >>= 1) ss += __shfl_xor(ss, o, 64);
  float vn = v * (1.f / sqrtf(ss * (1.f / 64.f) + 1e-6f));
  float p = __shfl_xor(vn, 32, 64);
  float ang = (float)te * exp2f(-13.287712379549449f * (float)(lane & 31) * (1.f / 32.f));
  float c = __cosf(ang), s = __sinf(ang);
  float outv = (lane < 32) ? (vn * c - p * s) : (p * s + vn * c);
  float gain = (slot < 8) ? q_gain[slot] * 0.125f : 1.f;
  *dst = __float2bfloat16(outv * gain);
}

// ------- V transpose: VB[row][256] -> Vt[b][kvh][64][2112] (zero pads), LDS-tiled -------
__global__ __launch_bounds__(256) void vrepack(const bf16* __restrict__ VB, bf16* __restrict__ Vt) {
  __shared__ short Ts[64][66];
  const int tt = blockIdx.x, kvh = blockIdx.y, b = blockIdx.z;
  const int tid = threadIdx.x;
#pragma unroll
  for (int r = 0; r < 2; ++r) {
    int e = r * 256 + tid, row = e >> 3, c8 = e & 7;
    int te = tt * 64 + row;
    uint4 val = {0u, 0u, 0u, 0u};
    if (te < kTEXT) val = *(const uint4*)(VB + ((size_t)(b * kTEXT + te)) * 256 + kvh * 64 + c8 * 8);
    union { uint4 u; short s[8]; } w; w.u = val;
#pragma unroll
    for (int i = 0; i < 8; ++i) Ts[row][c8 * 8 + i] = w.s[i];
  }
  __syncthreads();
#pragma unroll
  for (int r = 0; r < 2; ++r) {
    int e = r * 256 + tid, d = e >> 3, c8 = e & 7;
    union { uint4 u; short s[8]; } w;
#pragma unroll
    for (int i = 0; i < 8; ++i) w.s[i] = Ts[c8 * 8 + i][d];
    *(uint4*)(Vt + (((size_t)(b * 4 + kvh)) * 64 + d) * kTP + tt * 64 + c8 * 8) = w.u;
  }
}

// ---------------- MFMA causal flash attention: 1 head/block + register K/V prefetch ----------
__global__ __launch_bounds__(256) void attn_mfma(const bf16* __restrict__ Qp,
                                                 const bf16* __restrict__ Kp,
                                                 const bf16* __restrict__ Vt,
                                                 const float* __restrict__ attn_scale,
                                                 bf16* __restrict__ Y) {
  __shared__ short Ks[64][72];        // K tile [key][d]
  __shared__ short Vs[64][72];        // V^T tile [d][key]
  __shared__ short Ps[4][16][72];     // per-wave P [q][key]
  const int qt = (kQT - 1) - blockIdx.x;   // longest first
  const int h = blockIdx.y, b = blockIdx.z;
  const int kvh = h >> 1;
  const int tid = threadIdx.x, wave = tid >> 6, lane = tid & 63;
  const int quad = lane >> 4, l16 = lane & 15;

  short8 qf[2];
  {
    const bf16* qrow = Qp + (((size_t)(b * 8 + h)) * kTP + qt * 64 + wave * 16 + l16) * 64 + quad * 8;
    qf[0] = *(const short8*)(qrow);
    qf[1] = *(const short8*)(qrow + 32);
  }
  short8 ones;
#pragma unroll
  for (int i = 0; i < 8; ++i) ones[i] = (short)0x3F80;   // bf16 1.0

  const bf16* kbase = Kp + ((size_t)(b * 4 + kvh)) * kTP * 64;
  const bf16* vbase = Vt + ((size_t)(b * 4 + kvh)) * 64 * kTP;

  const int r0row = tid >> 3, r0c8 = tid & 7;            // staging coords (r=0)
  const int r1row = (256 + tid) >> 3, r1c8 = tid & 7;    // (r=1)

  f32x4 O[4] = {};
  f32x4 lacc = {};
  const int q_abs = qt * 64 + wave * 16 + l16;

  // prefetch tile 0 into registers
  uint4 kr0 = *(const uint4*)(kbase + (size_t)r0row * 64 + r0c8 * 8);
  uint4 kr1 = *(const uint4*)(kbase + (size_t)r1row * 64 + r1c8 * 8);
  uint4 vr0 = *(const uint4*)(vbase + (size_t)r0row * kTP + r0c8 * 8);
  uint4 vr1 = *(const uint4*)(vbase + (size_t)r1row * kTP + r1c8 * 8);

  for (int kt = 0; kt <= qt; ++kt) {
    __syncthreads();   // prior-iter LDS reads done
    *(uint4*)&Ks[r0row][r0c8 * 8] = kr0;
    *(uint4*)&Ks[r1row][r1c8 * 8] = kr1;
    *(uint4*)&Vs[r0row][r0c8 * 8] = vr0;
    *(uint4*)&Vs[r1row][r1c8 * 8] = vr1;
    if (kt < qt) {     // issue next tile's loads; latency hides behind compute
      int kn = (kt + 1) * 64;
      kr0 = *(const uint4*)(kbase + (size_t)(kn + r0row) * 64 + r0c8 * 8);
      kr1 = *(const uint4*)(kbase + (size_t)(kn + r1row) * 64 + r1c8 * 8);
      vr0 = *(const uint4*)(vbase + (size_t)r0row * kTP + kn + r0c8 * 8);
      vr1 = *(const uint4*)(vbase + (size_t)r1row * kTP + kn + r1c8 * 8);
    }
    __syncthreads();

    // ---- S^T = K * Q^T : rows = keys, cols = q ----
    f32x4 st[4] = {};
#pragma unroll
    for (int nb = 0; nb < 4; ++nb) {
      short8 ak0 = *(const short8*)&Ks[nb * 16 + l16][quad * 8];
      st[nb] = __builtin_amdgcn_mfma_f32_16x16x32_bf16(ak0, qf[0], st[nb], 0, 0, 0);
      short8 ak1 = *(const short8*)&Ks[nb * 16 + l16][32 + quad * 8];
      st[nb] = __builtin_amdgcn_mfma_f32_16x16x32_bf16(ak1, qf[1], st[nb], 0, 0, 0);
    }
    if (kt == qt) {
      int key0 = kt * 64 + quad * 4;
#pragma unroll
      for (int nb = 0; nb < 4; ++nb)
#pragma unroll
        for (int rg = 0; rg < 4; ++rg)
          if (key0 + nb * 16 + rg > q_abs) st[nb][rg] = -1e30f;
    }
#pragma unroll
    for (int nb = 0; nb < 4; ++nb) {
      union { unsigned long long q; bf16 hh[4]; } pw;
#pragma unroll
      for (int rg = 0; rg < 4; ++rg) pw.hh[rg] = __float2bfloat16(__expf(st[nb][rg]));
      *(unsigned long long*)&Ps[wave][l16][nb * 16 + quad * 4] = pw.q;
    }
    short8 pf0 = *(const short8*)&Ps[wave][l16][quad * 8];
    short8 pf1 = *(const short8*)&Ps[wave][l16][32 + quad * 8];
    lacc = __builtin_amdgcn_mfma_f32_16x16x32_bf16(pf0, ones, lacc, 0, 0, 0);
    lacc = __builtin_amdgcn_mfma_f32_16x16x32_bf16(pf1, ones, lacc, 0, 0, 0);
#pragma unroll
    for (int db = 0; db < 4; ++db) {
      short8 bv0 = *(const short8*)&Vs[db * 16 + l16][quad * 8];
      O[db] = __builtin_amdgcn_mfma_f32_16x16x32_bf16(pf0, bv0, O[db], 0, 0, 0);
      short8 bv1 = *(const short8*)&Vs[db * 16 + l16][32 + quad * 8];
      O[db] = __builtin_amdgcn_mfma_f32_16x16x32_bf16(pf1, bv1, O[db], 0, 0, 0);
    }
  }
  float asc = attn_scale[0];
#pragma unroll
  for (int rg = 0; rg < 4; ++rg) {
    int te_q = qt * 64 + wave * 16 + quad * 4 + rg;
    if (te_q < kNMETA || te_q >= kTEXT) continue;
    float so = asc / fmaxf(lacc[rg], 1e-30f);
    bf16* dst = Y + ((size_t)(b * kT + te_q - kNMETA)) * kDIM + h * 64 + l16;
#pragma unroll
    for (int db = 0; db < 4; ++db) dst[db * 16] = __float2bfloat16(O[db][rg] * so);
  }
}

// ---------------- SSM prep via MFMA: per head h, [64 bt rows] x [48 = dt|B|C] ----------------
__global__ __launch_bounds__(256) void ssm_prep(const bf16* __restrict__ sx,
                                                const float* __restrict__ dtw, const float* __restrict__ dtb,
                                                const float* __restrict__ Bw, const float* __restrict__ Cw,
                                                const float* __restrict__ logA,
                                                float* __restrict__ la, float* __restrict__ u,
                                                float* __restrict__ Cc) {
  __shared__ short Xs[64][72];
  __shared__ short Ws[48][72];
  const int bm = blockIdx.x * 64, h = blockIdx.y;
  const int tid = threadIdx.x, wave = tid >> 6, lane = tid & 63;
  const int quad = lane >> 4, l16 = lane & 15;
#pragma unroll
  for (int is = 0; is < 2; ++is) {
    int e = is * 256 + tid;
    int row = e >> 3, v = e & 7;
    uint4 val = *(const uint4*)(sx + ((size_t)(bm + row)) * 512 + h * 64 + v * 8);
    *(uint4*)&Xs[row][v * 8] = val;
  }
#pragma unroll
  for (int is = 0; is < 2; ++is) {
    int s = is * 256 + tid;
    if (s < 384) {
      int row = s >> 3, v = s & 7;
      const float* src = (row < 16) ? dtw + ((size_t)(h * 16 + row)) * 64
                       : (row < 32) ? Bw + ((size_t)(h * 16 + row - 16)) * 64
                                    : Cw + ((size_t)(h * 16 + row - 32)) * 64;
      float4 a0 = ((const float4*)src)[v * 2];
      float4 a1 = ((const float4*)src)[v * 2 + 1];
      *(uint4*)&Ws[row][v * 8] = pack8(a0, a1);
    }
  }
  __syncthreads();
  short8 af0 = *(const short8*)&Xs[wave * 16 + l16][quad * 8];
  short8 af1 = *(const short8*)&Xs[wave * 16 + l16][32 + quad * 8];
  f32x4 acc[3] = {};
#pragma unroll
  for (int nb = 0; nb < 3; ++nb) {
    short8 b0 = *(const short8*)&Ws[nb * 16 + l16][quad * 8];
    acc[nb] = __builtin_amdgcn_mfma_f32_16x16x32_bf16(af0, b0, acc[nb], 0, 0, 0);
    short8 b1 = *(const short8*)&Ws[nb * 16 + l16][32 + quad * 8];
    acc[nb] = __builtin_amdgcn_mfma_f32_16x16x32_bf16(af1, b1, acc[nb], 0, 0, 0);
  }
  float dtb_v = dtb[h * 16 + l16];
  float A_v = fminf(-expf(logA[h * 16 + l16]), 10.f);
#pragma unroll
  for (int rg = 0; rg < 4; ++rg) {
    int bt = bm + wave * 16 + quad * 4 + rg;
    size_t ix = (size_t)bt * 128 + h * 16 + l16;
    float raw = acc[0][rg] + dtb_v;
    float sp = fmaxf(raw, 0.f) + log1pf(expf(-fabsf(raw)));   // stable softplus
    float dt = fminf(sp, 1.f);
    float lav = fminf(fmaxf(dt * A_v, -0.5f), 0.f);
    la[ix] = lav;
    u[ix] = acc[1][rg] * dt;
    Cc[ix] = acc[2][rg];
  }
}

__global__ __launch_bounds__(256) void ssm_scan1(const float* __restrict__ la, const float* __restrict__ u,
                                                 bf16* __restrict__ hloc, bf16* __restrict__ Pb,
                                                 float* __restrict__ chH, float* __restrict__ chP) {
  int id = blockIdx.x * 256 + threadIdx.x;
  if (id >= 8192) return;
  int hs = id & 127, c = (id >> 7) & 31, b = id >> 12;
  float hv = 0.f, cum = 0.f;
  size_t base = ((size_t)b * kT) * 128 + hs;
  for (int i = 0; i < 64; ++i) {
    size_t ix = base + (size_t)(c * 64 + i) * 128;
    float lav = la[ix], uv = u[ix];
    cum += lav;
    hv = expf(lav) * hv + uv;
    hloc[ix] = __float2bfloat16(hv);
    Pb[ix] = __float2bfloat16(expf(fmaxf(cum, -30.f)));
  }
  chH[id] = hv;
  chP[id] = expf(fmaxf(cum, -30.f));
}

__global__ __launch_bounds__(256) void ssm_scan2(const float* __restrict__ chH,
                                                 const float* __restrict__ chP,
                                                 float* __restrict__ h0) {
  int id = threadIdx.x;
  int b = id >> 7, hs = id & 127;
  float h0v = 0.f;
  for (int c = 0; c < 32; ++c) {
    int ci = b * 4096 + c * 128 + hs;
    h0[ci] = h0v;
    h0v = chH[ci] + chP[ci] * h0v;
  }
}

// h = hloc + P*h0 ; y = sum Cc*h ; out = h@Ow^T + y*x0 ; 4 threads per (b,t,h), 16 d each
__global__ __launch_bounds__(256) void ssm_out(const bf16* __restrict__ hloc, const bf16* __restrict__ Pb,
                                               const float* __restrict__ h0, const float* __restrict__ Cc,
                                               const bf16* __restrict__ sx, const float* __restrict__ Ow,
                                               const float* __restrict__ ssm_scale, bf16* __restrict__ Y) {
  int id = blockIdx.x * 256 + threadIdx.x;   // kMX*8*4
  if (id >= kMX * 32) return;
  int d4 = id & 3, h = (id >> 2) & 7, t = (id >> 5) & 2047, b = id >> 16;
  size_t ix0 = ((size_t)(b * kT + t)) * 128 + h * 16;
  int h0b = b * 4096 + (t >> 6) * 128 + h * 16;
  float hv[16], y = 0.f;
#pragma unroll
  for (int s = 0; s < 16; ++s) {
    float v = __bfloat162float(hloc[ix0 + s]) + __bfloat162float(Pb[ix0 + s]) * h0[h0b + s];
    hv[s] = v;
    y += Cc[ix0 + s] * v;
  }
  float x0 = __bfloat162float(sx[((size_t)(b * kT + t)) * 512 + h * 64]);
  float scl = ssm_scale[0];
  const float* ow = Ow + ((size_t)h * 64 + d4 * 16) * 16;
  bf16* dst = Y + ((size_t)(b * kT + t)) * kDIM + 512 + h * 64 + d4 * 16;
  float yx = y * x0;
#pragma unroll
  for (int d = 0; d < 16; ++d) {
    float acc = yx;
    const float* owr = ow + d * 16;
#pragma unroll
    for (int s = 0; s < 16; ++s) acc += hv[s] * owr[s];
    dst[d] = __float2bfloat16(acc * scl);
  }
}

// ---------------- host ----------------
extern "C" void kernel_launch(void* const* d_in, const int* in_sizes, int n_in,
                              void* d_out, int out_size, void* d_ws, size_t ws_size,
                              hipStream_t stream) {
  (void)in_sizes; (void)n_in; (void)out_size; (void)ws_size;
  const float* x        = (const float*)d_in[0];
  const float* meta     = (const float*)d_in[1];
  const float* c_q_w    = (const float*)d_in[2];
  const float* c_k_w    = (const float*)d_in[3];
  const float* c_v_w    = (const float*)d_in[4];
  const float* q_gain   = (const float*)d_in[5];
  const float* ssm_in_w = (const float*)d_in[6];
  const float* proj_w   = (const float*)d_in[7];
  const float* attn_sc  = (const float*)d_in[8];
  const float* ssm_sc   = (const float*)d_in[9];
  const float* ssm_logA = (const float*)d_in[10];
  const float* ssm_Bw   = (const float*)d_in[11];
  const float* ssm_Cw   = (const float*)d_in[12];
  const float* ssm_dtw  = (const float*)d_in[13];
  const float* ssm_dtb  = (const float*)d_in[14];
  const float* ssm_Ow   = (const float*)d_in[15];

  char* w = (char*)d_ws;
  bf16*  XE = (bf16*)(w + oXE);
  bf16*  QB = (bf16*)(w + oQB);
  bf16*  KB = (bf16*)(w + oKB);
  bf16*  VB = (bf16*)(w + oVB);
  bf16*  SX = (bf16*)(w + oSX);
  bf16*  YB = (bf16*)(w + oYB);
  bf16*  QP = (bf16*)(w + oQP);
  bf16*  KP = (bf16*)(w + oKP);
  bf16*  VT = (bf16*)(w + oVT);
  bf16*  WQ = (bf16*)(w + oWQ);
  bf16*  WP = (bf16*)(w + oWP);
  float* LA = (float*)(w + oLA);
  float* UU = (float*)(w + oUU);
  float* CC = (float*)(w + oCC);
  bf16*  HL = (bf16*)(w + oHL);
  bf16*  PB = (bf16*)(w + oPB);
  float* CH = (float*)(w + oCH);
  float* CP = (float*)(w + oCP);
  float* H0 = (float*)(w + oH0);

  prep_all<<<(2560 + kMPAD) * 128 / 256, 256, 0, stream>>>(c_q_w, c_k_w, c_v_w, ssm_in_w, proj_w,
                                                           x, meta, WQ, WP, XE);

  gemm128<0><<<dim3(12, kMPAD / 128), 256, 0, stream>>>(XE, WQ, QB, KB, VB, SX);   // QKV+SX fused

  norm_rope_pack<<<(kB * kTP * 12) / 4, 256, 0, stream>>>(QB, KB, q_gain, QP, KP);
  vrepack<<<dim3(kQT, 4, kB), 256, 0, stream>>>(VB, VT);

  attn_mfma<<<dim3(kQT, 8, kB), 256, 0, stream>>>(QP, KP, VT, attn_sc, YB);

  ssm_prep<<<dim3(kMX / 64, 8), 256, 0, stream>>>(SX, ssm_dtw, ssm_dtb, ssm_Bw, ssm_Cw,
                                                  ssm_logA, LA, UU, CC);
  ssm_scan1<<<32, 256, 0, stream>>>(LA, UU, HL, PB, CH, CP);
  ssm_scan2<<<1, 256, 0, stream>>>(CH, CP, H0);
  ssm_out<<<kMX * 32 / 256, 256, 0, stream>>>(HL, PB, H0, CC, SX, ssm_Ow, ssm_sc, YB);

  gemm128<2><<<dim3(8, kMX / 128), 256, 0, stream>>>(YB, WP, d_out, nullptr, nullptr, nullptr);
}

// Round 9
// 231.484 us; speedup vs baseline: 1.2234x; 1.0501x over previous
//
#include <hip/hip_runtime.h>
#include <hip/hip_bf16.h>
#include <math.h>

typedef __hip_bfloat16 bf16;
typedef __attribute__((ext_vector_type(8))) short short8;   // 8 bf16 = 4 VGPRs (MFMA A/B frag)
typedef __attribute__((ext_vector_type(4))) float f32x4;    // MFMA C/D frag

static constexpr int kB = 2;
static constexpr int kT = 2048;
static constexpr int kDIM = 1024;
static constexpr int kNMETA = 4;
static constexpr int kTEXT = kT + kNMETA;   // 2052
static constexpr int kMEXT = kB * kTEXT;    // 4104
static constexpr int kMPAD = 4224;          // 33*128
static constexpr int kMX = kB * kT;         // 4096
static constexpr int kQT = 33;
static constexpr int kTP = 2112;            // 33*64

// ---------- workspace layout (bytes); ws ~268 MB ----------
static constexpr size_t oXE = 0;                                  // x_ext bf16 [4224][1024]
static constexpr size_t oYB = 0;                                  // aliases XE (dead after GEMMs)
static constexpr size_t oQB = 8650752;                            // Q bf16 [4224][512]
static constexpr size_t oKB = oQB + (size_t)kMPAD * 512 * 2;      // K bf16 [4224][256]
static constexpr size_t oVB = oKB + (size_t)kMPAD * 256 * 2;      // V bf16 [4224][256]
// SSM intermediates alias QB/KB/VB after attention:
static constexpr size_t oLA = oQB;                                // la f32 [4096][128]
static constexpr size_t oUU = oLA + (size_t)kMX * 128 * 4;
static constexpr size_t oCC = oUU + (size_t)kMX * 128 * 4;
static constexpr size_t oHL = oCC + (size_t)kMX * 128 * 4;        // hloc bf16
static constexpr size_t oPB = oHL + (size_t)kMX * 128 * 2;        // P    bf16
static constexpr size_t oCH = oPB + (size_t)kMX * 128 * 2;        // chunk H^T f32 [16384] (b,hs,c)
static constexpr size_t oCP = oCH + 16384 * 4;                    // chunk P^T f32 [16384]
static constexpr size_t oH0 = oCP + 16384 * 4;                    // h0 f32 [16384] (b,c,hs)
static constexpr size_t oSX = oVB + (size_t)kMPAD * 256 * 2;      // ssm x bf16 [4096][512]
static constexpr size_t oQP = oSX + (size_t)kMX * 512 * 2;        // Qp bf16 [b][8][2112][64]
static constexpr size_t oKP = oQP + (size_t)kB * 8 * kTP * 64 * 2;// Kp bf16 [b][4][2112][64]
static constexpr size_t oVT = oKP + (size_t)kB * 4 * kTP * 64 * 2;// Vt bf16 [b][4][64][2112]
static constexpr size_t oWQ = oQP;                                // WQKV+WSX bf16 [1536][1024] (early)
static constexpr size_t oWP = oVT + (size_t)kB * 4 * 64 * kTP * 2;// Wproj bf16 [1024][1024]
static constexpr size_t oAO = 33554432;                           // attn partial O f32 [2][b][8][2112][64]
static constexpr size_t oAL = oAO + (size_t)2 * kB * 8 * kTP * 64 * 4;  // partial l f32 [2][b][8][2112]

#define GLD_LDS16(gp, lp)                                                          \
  __builtin_amdgcn_global_load_lds((const __attribute__((address_space(1))) void*)(gp), \
                                   (__attribute__((address_space(3))) void*)(lp), 16, 0, 0)

__device__ __forceinline__ uint4 pack8(float4 a, float4 b) {
  union { bf16 h[8]; uint4 v; } u;
  u.h[0] = __float2bfloat16(a.x); u.h[1] = __float2bfloat16(a.y);
  u.h[2] = __float2bfloat16(a.z); u.h[3] = __float2bfloat16(a.w);
  u.h[4] = __float2bfloat16(b.x); u.h[5] = __float2bfloat16(b.y);
  u.h[6] = __float2bfloat16(b.z); u.h[7] = __float2bfloat16(b.w);
  return u.v;
}

// ---------------- all weight converts + x_ext build in one launch ----------------
__global__ __launch_bounds__(256) void prep_all(const float* __restrict__ cq, const float* __restrict__ ck,
                                                const float* __restrict__ cv, const float* __restrict__ sw,
                                                const float* __restrict__ pw,
                                                const float* __restrict__ x, const float* __restrict__ meta,
                                                bf16* __restrict__ wqkvsx, bf16* __restrict__ wproj,
                                                bf16* __restrict__ xe) {
  int i = blockIdx.x * 256 + threadIdx.x;
  int row = i >> 7, v = i & 127;
  if (row < 2560) {
    const float* src; bf16* dst;
    if (row < 512)       { src = cq + (size_t)row * 1024;          dst = wqkvsx + (size_t)row * 1024; }
    else if (row < 768)  { src = ck + (size_t)(row - 512) * 1024;  dst = wqkvsx + (size_t)row * 1024; }
    else if (row < 1024) { src = cv + (size_t)(row - 768) * 1024;  dst = wqkvsx + (size_t)row * 1024; }
    else if (row < 1536) { src = sw + (size_t)(row - 1024) * 1024; dst = wqkvsx + (size_t)row * 1024; }
    else                 { src = pw + (size_t)(row - 1536) * 1024; dst = wproj + (size_t)(row - 1536) * 1024; }
    float4 a0 = ((const float4*)src)[v * 2], a1 = ((const float4*)src)[v * 2 + 1];
    ((uint4*)dst)[v] = pack8(a0, a1);
  } else {
    int r = row - 2560;
    if (r >= kMPAD) return;
    uint4 val = {0u, 0u, 0u, 0u};
    if (r < kMEXT) {
      int b = r / kTEXT, te = r - b * kTEXT;
      const float* src = (te < kNMETA) ? (meta + (size_t)te * kDIM)
                                       : (x + ((size_t)b * kT + (te - kNMETA)) * kDIM);
      float4 a0 = ((const float4*)src)[v * 2];
      float4 a1 = ((const float4*)src)[v * 2 + 1];
      val = pack8(a0, a1);
    }
    ((uint4*)(xe + (size_t)r * kDIM))[v] = val;
  }
}

// ================= 128x64-tile bf16 GEMM (K=1024, BK=32), global_load_lds staging =========
// MODE 0: fused QKV+SX (epilogue scatter incl. SX row-remap). MODE 2: proj (f32 out).
template <int MODE>
__global__ __launch_bounds__(256) void gemm_t(const bf16* __restrict__ A,
                                              const bf16* __restrict__ W,
                                              void* __restrict__ O0, void* __restrict__ O1,
                                              void* __restrict__ O2, void* __restrict__ O3) {
  __shared__ short As[128 * 32];   // 8 KB
  __shared__ short Bs[64 * 32];    // 4 KB
  const int tid = threadIdx.x;
  const int wave = tid >> 6, lane = tid & 63;
  const int quad = lane >> 4, l16 = lane & 15;
  const int bm = blockIdx.y * 128, bn = blockIdx.x * 64;
  const int srow = tid >> 2, scol = (tid & 3) * 8;
  const bf16* ag0 = A + (size_t)(bm + srow) * 1024 + scol;
  const bf16* ag1 = A + (size_t)(bm + 64 + srow) * 1024 + scol;
  const bf16* bg0 = W + (size_t)(bn + srow) * 1024 + scol;
  char* asb = (char*)As + wave * 1024;
  char* bsb = (char*)Bs + wave * 1024;
  f32x4 acc[2][4] = {};
  for (int k0 = 0; k0 < 1024; k0 += 32) {
    __syncthreads();
    GLD_LDS16(ag0, asb);
    GLD_LDS16(ag1, asb + 4096);
    GLD_LDS16(bg0, bsb);
    ag0 += 32; ag1 += 32; bg0 += 32;
    __syncthreads();
    short8 af[2], bfr[4];
#pragma unroll
    for (int mi = 0; mi < 2; ++mi)
      af[mi] = *(const short8*)((const char*)As + (size_t)(wave * 32 + mi * 16 + l16) * 64 + quad * 16);
#pragma unroll
    for (int ni = 0; ni < 4; ++ni)
      bfr[ni] = *(const short8*)((const char*)Bs + (size_t)(ni * 16 + l16) * 64 + quad * 16);
#pragma unroll
    for (int mi = 0; mi < 2; ++mi)
#pragma unroll
      for (int ni = 0; ni < 4; ++ni)
        acc[mi][ni] = __builtin_amdgcn_mfma_f32_16x16x32_bf16(af[mi], bfr[ni], acc[mi][ni], 0, 0, 0);
  }
#pragma unroll
  for (int mi = 0; mi < 2; ++mi)
#pragma unroll
    for (int ni = 0; ni < 4; ++ni) {
      int colg = bn + ni * 16 + l16;
#pragma unroll
      for (int r = 0; r < 4; ++r) {
        int row = bm + wave * 32 + mi * 16 + quad * 4 + r;
        float val = acc[mi][ni][r];
        if constexpr (MODE == 2) {
          ((float*)O0)[(size_t)row * 1024 + colg] = val;
        } else {
          if (colg < 512)       ((bf16*)O0)[(size_t)row * 512 + colg]        = __float2bfloat16(val);
          else if (colg < 768)  ((bf16*)O1)[(size_t)row * 256 + colg - 512]  = __float2bfloat16(val);
          else if (colg < 1024) ((bf16*)O2)[(size_t)row * 256 + colg - 768]  = __float2bfloat16(val);
          else if (row < kMEXT) {
            int bb = row >= kTEXT ? 1 : 0;
            int te = row - bb * kTEXT;
            if (te >= kNMETA)
              ((bf16*)O3)[((size_t)(bb * kT + te - kNMETA)) * 512 + colg - 1024] = __float2bfloat16(val);
          }
        }
      }
    }
}

// ------- RMSnorm + RoPE (+q_gain, +1/sqrt(D)) -> packed Qp[b][8][2112][64], Kp[b][4][2112][64]
__global__ __launch_bounds__(256) void norm_rope_pack(const bf16* __restrict__ QB,
                                                      const bf16* __restrict__ KB,
                                                      const float* __restrict__ q_gain,
                                                      bf16* __restrict__ Qp, bf16* __restrict__ Kp) {
  int job = blockIdx.x * 4 + (threadIdx.x >> 6);
  if (job >= kB * kTP * 12) return;
  int lane = threadIdx.x & 63;
  int slot = job % 12, rowp = job / 12;
  int b = rowp / kTP, te = rowp % kTP;
  bf16* dst = (slot < 8) ? Qp + (((size_t)(b * 8 + slot)) * kTP + te) * 64 + lane
                         : Kp + (((size_t)(b * 4 + slot - 8)) * kTP + te) * 64 + lane;
  if (te >= kTEXT) { *dst = __float2bfloat16(0.f); return; }
  const bf16* src = (slot < 8) ? QB + ((size_t)(b * kTEXT + te)) * 512 + slot * 64 + lane
                               : KB + ((size_t)(b * kTEXT + te)) * 256 + (slot - 8) * 64 + lane;
  float v = __bfloat162float(*src);
  float ss = v * v;
#pragma unroll
  for (int o = 32; o > 0; o >>= 1) ss += __shfl_xor(ss, o, 64);
  float vn = v * (1.f / sqrtf(ss * (1.f / 64.f) + 1e-6f));
  float p = __shfl_xor(vn, 32, 64);
  float ang = (float)te * exp2f(-13.287712379549449f * (float)(lane & 31) * (1.f / 32.f));
  float c = __cosf(ang), s = __sinf(ang);
  float outv = (lane < 32) ? (vn * c - p * s) : (p * s + vn * c);
  float gain = (slot < 8) ? q_gain[slot] * 0.125f : 1.f;
  *dst = __float2bfloat16(outv * gain);
}

// ------- V transpose: VB[row][256] -> Vt[b][kvh][64][2112] (zero pads), LDS-tiled -------
__global__ __launch_bounds__(256) void vrepack(const bf16* __restrict__ VB, bf16* __restrict__ Vt) {
  __shared__ short Ts[64][66];
  const int tt = blockIdx.x, kvh = blockIdx.y, b = blockIdx.z;
  const int tid = threadIdx.x;
#pragma unroll
  for (int r = 0; r < 2; ++r) {
    int e = r * 256 + tid, row = e >> 3, c8 = e & 7;
    int te = tt * 64 + row;
    uint4 val = {0u, 0u, 0u, 0u};
    if (te < kTEXT) val = *(const uint4*)(VB + ((size_t)(b * kTEXT + te)) * 256 + kvh * 64 + c8 * 8);
    union { uint4 u; short s[8]; } w; w.u = val;
#pragma unroll
    for (int i = 0; i < 8; ++i) Ts[row][c8 * 8 + i] = w.s[i];
  }
  __syncthreads();
#pragma unroll
  for (int r = 0; r < 2; ++r) {
    int e = r * 256 + tid, d = e >> 3, c8 = e & 7;
    union { uint4 u; short s[8]; } w;
#pragma unroll
    for (int i = 0; i < 8; ++i) w.s[i] = Ts[c8 * 8 + i][d];
    *(uint4*)(Vt + (((size_t)(b * 4 + kvh)) * 64 + d) * kTP + tt * 64 + c8 * 8) = w.u;
  }
}

// ------- MFMA flash attention, kv-split x2: partial O (unscaled) + l to f32 buffers -------
__global__ __launch_bounds__(256) void attn_part(const bf16* __restrict__ Qp,
                                                 const bf16* __restrict__ Kp,
                                                 const bf16* __restrict__ Vt,
                                                 float* __restrict__ AO, float* __restrict__ AL) {
  __shared__ short Ks[64][72];
  __shared__ short Vs[64][72];
  __shared__ short Ps[4][16][72];
  const int part = blockIdx.x & 1;
  const int qt = (kQT - 1) - (blockIdx.x >> 1);   // longest first
  const int h = blockIdx.y, b = blockIdx.z;
  const int kvh = h >> 1;
  const int tid = threadIdx.x, wave = tid >> 6, lane = tid & 63;
  const int quad = lane >> 4, l16 = lane & 15;
  const int hsplit = (qt + 2) >> 1;
  const int kt_begin = part == 0 ? 0 : hsplit;
  const int kt_end = part == 0 ? hsplit : qt + 1;   // exclusive

  short8 qf[2];
  {
    const bf16* qrow = Qp + (((size_t)(b * 8 + h)) * kTP + qt * 64 + wave * 16 + l16) * 64 + quad * 8;
    qf[0] = *(const short8*)(qrow);
    qf[1] = *(const short8*)(qrow + 32);
  }
  short8 ones;
#pragma unroll
  for (int i = 0; i < 8; ++i) ones[i] = (short)0x3F80;   // bf16 1.0

  const bf16* kbase = Kp + ((size_t)(b * 4 + kvh)) * kTP * 64;
  const bf16* vbase = Vt + ((size_t)(b * 4 + kvh)) * 64 * kTP;

  const int r0row = tid >> 3, r0c8 = tid & 7;
  const int r1row = (256 + tid) >> 3, r1c8 = tid & 7;

  f32x4 O[4] = {};
  f32x4 lacc = {};
  const int q_abs = qt * 64 + wave * 16 + l16;

  // prefetch first tile (in-bounds even if range empty: kTP-padded)
  uint4 kr0 = *(const uint4*)(kbase + (size_t)(kt_begin * 64 + r0row) * 64 + r0c8 * 8);
  uint4 kr1 = *(const uint4*)(kbase + (size_t)(kt_begin * 64 + r1row) * 64 + r1c8 * 8);
  uint4 vr0 = *(const uint4*)(vbase + (size_t)r0row * kTP + kt_begin * 64 + r0c8 * 8);
  uint4 vr1 = *(const uint4*)(vbase + (size_t)r1row * kTP + kt_begin * 64 + r1c8 * 8);

  for (int kt = kt_begin; kt < kt_end; ++kt) {
    __syncthreads();
    *(uint4*)&Ks[r0row][r0c8 * 8] = kr0;
    *(uint4*)&Ks[r1row][r1c8 * 8] = kr1;
    *(uint4*)&Vs[r0row][r0c8 * 8] = vr0;
    *(uint4*)&Vs[r1row][r1c8 * 8] = vr1;
    if (kt + 1 < kt_end) {
      int kn = (kt + 1) * 64;
      kr0 = *(const uint4*)(kbase + (size_t)(kn + r0row) * 64 + r0c8 * 8);
      kr1 = *(const uint4*)(kbase + (size_t)(kn + r1row) * 64 + r1c8 * 8);
      vr0 = *(const uint4*)(vbase + (size_t)r0row * kTP + kn + r0c8 * 8);
      vr1 = *(const uint4*)(vbase + (size_t)r1row * kTP + kn + r1c8 * 8);
    }
    __syncthreads();

    f32x4 st[4] = {};
#pragma unroll
    for (int nb = 0; nb < 4; ++nb) {
      short8 ak0 = *(const short8*)&Ks[nb * 16 + l16][quad * 8];
      st[nb] = __builtin_amdgcn_mfma_f32_16x16x32_bf16(ak0, qf[0], st[nb], 0, 0, 0);
      short8 ak1 = *(const short8*)&Ks[nb * 16 + l16][32 + quad * 8];
      st[nb] = __builtin_amdgcn_mfma_f32_16x16x32_bf16(ak1, qf[1], st[nb], 0, 0, 0);
    }
    if (kt == qt) {
      int key0 = kt * 64 + quad * 4;
#pragma unroll
      for (int nb = 0; nb < 4; ++nb)
#pragma unroll
        for (int rg = 0; rg < 4; ++rg)
          if (key0 + nb * 16 + rg > q_abs) st[nb][rg] = -1e30f;
    }
#pragma unroll
    for (int nb = 0; nb < 4; ++nb) {
      union { unsigned long long q; bf16 hh[4]; } pw;
#pragma unroll
      for (int rg = 0; rg < 4; ++rg) pw.hh[rg] = __float2bfloat16(__expf(st[nb][rg]));
      *(unsigned long long*)&Ps[wave][l16][nb * 16 + quad * 4] = pw.q;
    }
    short8 pf0 = *(const short8*)&Ps[wave][l16][quad * 8];
    short8 pf1 = *(const short8*)&Ps[wave][l16][32 + quad * 8];
    lacc = __builtin_amdgcn_mfma_f32_16x16x32_bf16(pf0, ones, lacc, 0, 0, 0);
    lacc = __builtin_amdgcn_mfma_f32_16x16x32_bf16(pf1, ones, lacc, 0, 0, 0);
#pragma unroll
    for (int db = 0; db < 4; ++db) {
      short8 bv0 = *(const short8*)&Vs[db * 16 + l16][quad * 8];
      O[db] = __builtin_amdgcn_mfma_f32_16x16x32_bf16(pf0, bv0, O[db], 0, 0, 0);
      short8 bv1 = *(const short8*)&Vs[db * 16 + l16][32 + quad * 8];
      O[db] = __builtin_amdgcn_mfma_f32_16x16x32_bf16(pf1, bv1, O[db], 0, 0, 0);
    }
  }
  // ---- write unscaled partials (all 64 q rows, incl. pads) ----
  size_t hb = (((size_t)part * 2 + b) * 8 + h);
  float* aoB = AO + hb * kTP * 64;
  float* alB = AL + hb * kTP;
#pragma unroll
  for (int rg = 0; rg < 4; ++rg) {
    int q = qt * 64 + wave * 16 + quad * 4 + rg;
    float* dst = aoB + (size_t)q * 64 + l16;
#pragma unroll
    for (int db = 0; db < 4; ++db) dst[db * 16] = O[db][rg];
    if (l16 == 0) alB[q] = lacc[rg];
  }
}

// ------- combine the 2 kv-split partials -> Y bf16 -------
__global__ __launch_bounds__(256) void attn_combine(const float* __restrict__ AO,
                                                    const float* __restrict__ AL,
                                                    const float* __restrict__ attn_scale,
                                                    bf16* __restrict__ Y) {
  int id = blockIdx.x * 256 + threadIdx.x;     // 2*8*2112*4
  int d16 = id & 3;
  int tmp = id >> 2;
  int q = tmp % kTP; tmp /= kTP;
  int h = tmp & 7, b = tmp >> 3;
  if (q < kNMETA || q >= kTEXT) return;
  size_t hb0 = ((size_t)b * 8 + h), hb1 = ((size_t)(2 + b) * 8 + h);
  float l = AL[hb0 * kTP + q] + AL[hb1 * kTP + q];
  float so = attn_scale[0] / fmaxf(l, 1e-30f);
  const float4* p0 = (const float4*)(AO + (hb0 * kTP + q) * 64 + d16 * 16);
  const float4* p1 = (const float4*)(AO + (hb1 * kTP + q) * 64 + d16 * 16);
  bf16* dst = Y + ((size_t)(b * kT + q - kNMETA)) * kDIM + h * 64 + d16 * 16;
#pragma unroll
  for (int i = 0; i < 4; ++i) {
    float4 a = p0[i], c = p1[i];
    dst[i * 4 + 0] = __float2bfloat16((a.x + c.x) * so);
    dst[i * 4 + 1] = __float2bfloat16((a.y + c.y) * so);
    dst[i * 4 + 2] = __float2bfloat16((a.z + c.z) * so);
    dst[i * 4 + 3] = __float2bfloat16((a.w + c.w) * so);
  }
}

// ---------------- SSM prep via MFMA: per head h, [64 bt rows] x [48 = dt|B|C] ----------------
__global__ __launch_bounds__(256) void ssm_prep(const bf16* __restrict__ sx,
                                                const float* __restrict__ dtw, const float* __restrict__ dtb,
                                                const float* __restrict__ Bw, const float* __restrict__ Cw,
                                                const float* __restrict__ logA,
                                                float* __restrict__ la, float* __restrict__ u,
                                                float* __restrict__ Cc) {
  __shared__ short Xs[64][72];
  __shared__ short Ws[48][72];
  const int bm = blockIdx.x * 64, h = blockIdx.y;
  const int tid = threadIdx.x, wave = tid >> 6, lane = tid & 63;
  const int quad = lane >> 4, l16 = lane & 15;
#pragma unroll
  for (int is = 0; is < 2; ++is) {
    int e = is * 256 + tid;
    int row = e >> 3, v = e & 7;
    uint4 val = *(const uint4*)(sx + ((size_t)(bm + row)) * 512 + h * 64 + v * 8);
    *(uint4*)&Xs[row][v * 8] = val;
  }
#pragma unroll
  for (int is = 0; is < 2; ++is) {
    int s = is * 256 + tid;
    if (s < 384) {
      int row = s >> 3, v = s & 7;
      const float* src = (row < 16) ? dtw + ((size_t)(h * 16 + row)) * 64
                       : (row < 32) ? Bw + ((size_t)(h * 16 + row - 16)) * 64
                                    : Cw + ((size_t)(h * 16 + row - 32)) * 64;
      float4 a0 = ((const float4*)src)[v * 2];
      float4 a1 = ((const float4*)src)[v * 2 + 1];
      *(uint4*)&Ws[row][v * 8] = pack8(a0, a1);
    }
  }
  __syncthreads();
  short8 af0 = *(const short8*)&Xs[wave * 16 + l16][quad * 8];
  short8 af1 = *(const short8*)&Xs[wave * 16 + l16][32 + quad * 8];
  f32x4 acc[3] = {};
#pragma unroll
  for (int nb = 0; nb < 3; ++nb) {
    short8 b0 = *(const short8*)&Ws[nb * 16 + l16][quad * 8];
    acc[nb] = __builtin_amdgcn_mfma_f32_16x16x32_bf16(af0, b0, acc[nb], 0, 0, 0);
    short8 b1 = *(const short8*)&Ws[nb * 16 + l16][32 + quad * 8];
    acc[nb] = __builtin_amdgcn_mfma_f32_16x16x32_bf16(af1, b1, acc[nb], 0, 0, 0);
  }
  float dtb_v = dtb[h * 16 + l16];
  float A_v = fminf(-expf(logA[h * 16 + l16]), 10.f);
#pragma unroll
  for (int rg = 0; rg < 4; ++rg) {
    int bt = bm + wave * 16 + quad * 4 + rg;
    size_t ix = (size_t)bt * 128 + h * 16 + l16;
    float raw = acc[0][rg] + dtb_v;
    float sp = fmaxf(raw, 0.f) + log1pf(expf(-fabsf(raw)));   // stable softplus
    float dt = fminf(sp, 1.f);
    float lav = fminf(fmaxf(dt * A_v, -0.5f), 0.f);
    la[ix] = lav;
    u[ix] = acc[1][rg] * dt;
    Cc[ix] = acc[2][rg];
  }
}

// phase 1: 32-step sub-chunks; chain summaries written TRANSPOSED (b, hs, c)
__global__ __launch_bounds__(256) void ssm_scan1(const float* __restrict__ la, const float* __restrict__ u,
                                                 bf16* __restrict__ hloc, bf16* __restrict__ Pb,
                                                 float* __restrict__ chHt, float* __restrict__ chPt) {
  int id = blockIdx.x * 256 + threadIdx.x;   // b*8192 + c*128 + hs, c in [0,64)
  if (id >= 16384) return;
  int hs = id & 127, c = (id >> 7) & 63, b = id >> 13;
  float hv = 0.f, cum = 0.f;
  size_t base = ((size_t)b * kT) * 128 + hs;
  for (int i = 0; i < 32; ++i) {
    size_t ix = base + (size_t)(c * 32 + i) * 128;
    float lav = la[ix], uv = u[ix];
    cum += lav;
    hv = expf(lav) * hv + uv;
    hloc[ix] = __float2bfloat16(hv);
    Pb[ix] = __float2bfloat16(expf(fmaxf(cum, -30.f)));
  }
  int t = b * 8192 + hs * 64 + c;
  chHt[t] = hv;
  chPt[t] = expf(fmaxf(cum, -30.f));
}

// phase 2: 64-lane Hillis-Steele composition scan per chain; h0 (exclusive) in (b,c,hs) layout
__global__ __launch_bounds__(256) void ssm_scan2(const float* __restrict__ chHt,
                                                 const float* __restrict__ chPt,
                                                 float* __restrict__ h0) {
  int id = blockIdx.x * 256 + threadIdx.x;   // 16384: chain = id>>6 (wave-aligned), lane=c
  int c = id & 63;
  int chain = id >> 6;        // b*128 + hs
  int b = chain >> 7, hs = chain & 127;
  int t = b * 8192 + hs * 64 + c;
  float H = chHt[t], P = chPt[t];
#pragma unroll
  for (int off = 1; off < 64; off <<= 1) {
    float Hp = __shfl_up(H, off, 64);
    float Pp = __shfl_up(P, off, 64);
    if (c >= off) { H = H + P * Hp; P = P * Pp; }
  }
  float Hex = __shfl_up(H, 1, 64);
  if (c == 0) Hex = 0.f;
  h0[b * 8192 + c * 128 + hs] = Hex;
}

// h = hloc + P*h0 ; y = sum Cc*h ; out = h@Ow^T + y*x0 ; 4 threads per (b,t,h), 16 d each
__global__ __launch_bounds__(256) void ssm_out(const bf16* __restrict__ hloc, const bf16* __restrict__ Pb,
                                               const float* __restrict__ h0, const float* __restrict__ Cc,
                                               const bf16* __restrict__ sx, const float* __restrict__ Ow,
                                               const float* __restrict__ ssm_scale, bf16* __restrict__ Y) {
  int id = blockIdx.x * 256 + threadIdx.x;   // kMX*8*4
  if (id >= kMX * 32) return;
  int d4 = id & 3, h = (id >> 2) & 7, t = (id >> 5) & 2047, b = id >> 16;
  size_t ix0 = ((size_t)(b * kT + t)) * 128 + h * 16;
  int h0b = b * 8192 + (t >> 5) * 128 + h * 16;
  float hv[16], y = 0.f;
#pragma unroll
  for (int s = 0; s < 16; ++s) {
    float v = __bfloat162float(hloc[ix0 + s]) + __bfloat162float(Pb[ix0 + s]) * h0[h0b + s];
    hv[s] = v;
    y += Cc[ix0 + s] * v;
  }
  float x0 = __bfloat162float(sx[((size_t)(b * kT + t)) * 512 + h * 64]);
  float scl = ssm_scale[0];
  const float* ow = Ow + ((size_t)h * 64 + d4 * 16) * 16;
  bf16* dst = Y + ((size_t)(b * kT + t)) * kDIM + 512 + h * 64 + d4 * 16;
  float yx = y * x0;
#pragma unroll
  for (int d = 0; d < 16; ++d) {
    float acc = yx;
    const float* owr = ow + d * 16;
#pragma unroll
    for (int s = 0; s < 16; ++s) acc += hv[s] * owr[s];
    dst[d] = __float2bfloat16(acc * scl);
  }
}

// ---------------- host ----------------
extern "C" void kernel_launch(void* const* d_in, const int* in_sizes, int n_in,
                              void* d_out, int out_size, void* d_ws, size_t ws_size,
                              hipStream_t stream) {
  (void)in_sizes; (void)n_in; (void)out_size; (void)ws_size;
  const float* x        = (const float*)d_in[0];
  const float* meta     = (const float*)d_in[1];
  const float* c_q_w    = (const float*)d_in[2];
  const float* c_k_w    = (const float*)d_in[3];
  const float* c_v_w    = (const float*)d_in[4];
  const float* q_gain   = (const float*)d_in[5];
  const float* ssm_in_w = (const float*)d_in[6];
  const float* proj_w   = (const float*)d_in[7];
  const float* attn_sc  = (const float*)d_in[8];
  const float* ssm_sc   = (const float*)d_in[9];
  const float* ssm_logA = (const float*)d_in[10];
  const float* ssm_Bw   = (const float*)d_in[11];
  const float* ssm_Cw   = (const float*)d_in[12];
  const float* ssm_dtw  = (const float*)d_in[13];
  const float* ssm_dtb  = (const float*)d_in[14];
  const float* ssm_Ow   = (const float*)d_in[15];

  char* w = (char*)d_ws;
  bf16*  XE = (bf16*)(w + oXE);
  bf16*  QB = (bf16*)(w + oQB);
  bf16*  KB = (bf16*)(w + oKB);
  bf16*  VB = (bf16*)(w + oVB);
  bf16*  SX = (bf16*)(w + oSX);
  bf16*  YB = (bf16*)(w + oYB);
  bf16*  QP = (bf16*)(w + oQP);
  bf16*  KP = (bf16*)(w + oKP);
  bf16*  VT = (bf16*)(w + oVT);
  bf16*  WQ = (bf16*)(w + oWQ);
  bf16*  WP = (bf16*)(w + oWP);
  float* LA = (float*)(w + oLA);
  float* UU = (float*)(w + oUU);
  float* CC = (float*)(w + oCC);
  bf16*  HL = (bf16*)(w + oHL);
  bf16*  PB = (bf16*)(w + oPB);
  float* CH = (float*)(w + oCH);
  float* CP = (float*)(w + oCP);
  float* H0 = (float*)(w + oH0);
  float* AO = (float*)(w + oAO);
  float* AL = (float*)(w + oAL);

  prep_all<<<(2560 + kMPAD) * 128 / 256, 256, 0, stream>>>(c_q_w, c_k_w, c_v_w, ssm_in_w, proj_w,
                                                           x, meta, WQ, WP, XE);

  gemm_t<0><<<dim3(24, kMPAD / 128), 256, 0, stream>>>(XE, WQ, QB, KB, VB, SX);   // QKV+SX fused

  norm_rope_pack<<<(kB * kTP * 12) / 4, 256, 0, stream>>>(QB, KB, q_gain, QP, KP);
  vrepack<<<dim3(kQT, 4, kB), 256, 0, stream>>>(VB, VT);

  attn_part<<<dim3(kQT * 2, 8, kB), 256, 0, stream>>>(QP, KP, VT, AO, AL);
  attn_combine<<<(2 * 8 * kTP * 4) / 256, 256, 0, stream>>>(AO, AL, attn_sc, YB);

  ssm_prep<<<dim3(kMX / 64, 8), 256, 0, stream>>>(SX, ssm_dtw, ssm_dtb, ssm_Bw, ssm_Cw,
                                                  ssm_logA, LA, UU, CC);
  ssm_scan1<<<64, 256, 0, stream>>>(LA, UU, HL, PB, CH, CP);
  ssm_scan2<<<64, 256, 0, stream>>>(CH, CP, H0);
  ssm_out<<<kMX * 32 / 256, 256, 0, stream>>>(HL, PB, H0, CC, SX, ssm_Ow, ssm_sc, YB);

  gemm_t<2><<<dim3(16, kMX / 128), 256, 0, stream>>>(YB, WP, d_out, nullptr, nullptr, nullptr);
}

// Round 10
// 215.683 us; speedup vs baseline: 1.3130x; 1.0733x over previous
//
#include <hip/hip_runtime.h>
#include <hip/hip_bf16.h>
#include <math.h>

typedef __hip_bfloat16 bf16;
typedef __attribute__((ext_vector_type(8))) short short8;   // 8 bf16 = 4 VGPRs (MFMA A/B frag)
typedef __attribute__((ext_vector_type(4))) float f32x4;    // MFMA C/D frag

static constexpr int kB = 2;
static constexpr int kT = 2048;
static constexpr int kDIM = 1024;
static constexpr int kNMETA = 4;
static constexpr int kTEXT = kT + kNMETA;   // 2052
static constexpr int kMEXT = kB * kTEXT;    // 4104
static constexpr int kMPAD = 4224;          // 33*128
static constexpr int kMX = kB * kT;         // 4096
static constexpr int kQT = 33;
static constexpr int kTP = 2112;            // 33*64

// ---------- workspace layout (bytes); ws ~268 MB ----------
static constexpr size_t oXE = 0;                                  // x_ext bf16 [4224][1024]
static constexpr size_t oYB = 0;                                  // aliases XE (dead after GEMMs)
static constexpr size_t oLU = 8650752;                            // la/u interleaved f32x2 [4096][128][2]
static constexpr size_t oCC = oLU + (size_t)kMX * 128 * 8;        // Cc f32 [4096][128]
static constexpr size_t oHL = oCC + (size_t)kMX * 128 * 4;        // hloc bf16
static constexpr size_t oPB = oHL + (size_t)kMX * 128 * 2;        // P    bf16
static constexpr size_t oCH = oPB + (size_t)kMX * 128 * 2;        // chunk H^T f32 [16384] (b,hs,c)
static constexpr size_t oCP = oCH + 16384 * 4;                    // chunk P^T f32 [16384]
static constexpr size_t oH0 = oCP + 16384 * 4;                    // h0 f32 [16384] (b,c,hs)
static constexpr size_t oSX = oLU + (size_t)kMX * 128 * 8 + (size_t)kMX * 128 * 12;  // ssm x bf16 [4096][512]
static constexpr size_t oQP = oSX + (size_t)kMX * 512 * 2;        // Qp bf16 [b][8][2112][64]
static constexpr size_t oKP = oQP + (size_t)kB * 8 * kTP * 64 * 2;// Kp bf16 [b][4][2112][64]
static constexpr size_t oVT = oKP + (size_t)kB * 4 * kTP * 64 * 2;// Vt bf16 [b][4][64][2112]
static constexpr size_t oWP = oVT + (size_t)kB * 4 * 64 * kTP * 2;// Wproj bf16 [1024][1024]
static constexpr size_t oWQ = oWP + (size_t)1024 * 1024 * 2;      // WQKV+WSX bf16 [1536][1024]
static constexpr size_t oAO = 100663296;                          // attn partial O f32 [2][b][8][2112][64]
static constexpr size_t oAL = oAO + (size_t)2 * kB * 8 * kTP * 64 * 4;  // partial l f32 [2][b][8][2112]

#define GLD_LDS16(gp, lp)                                                          \
  __builtin_amdgcn_global_load_lds((const __attribute__((address_space(1))) void*)(gp), \
                                   (__attribute__((address_space(3))) void*)(lp), 16, 0, 0)

__device__ __forceinline__ uint4 pack8(float4 a, float4 b) {
  union { bf16 h[8]; uint4 v; } u;
  u.h[0] = __float2bfloat16(a.x); u.h[1] = __float2bfloat16(a.y);
  u.h[2] = __float2bfloat16(a.z); u.h[3] = __float2bfloat16(a.w);
  u.h[4] = __float2bfloat16(b.x); u.h[5] = __float2bfloat16(b.y);
  u.h[6] = __float2bfloat16(b.z); u.h[7] = __float2bfloat16(b.w);
  return u.v;
}

// ---- prep: weight converts + x_ext build + QP/KP/VT tail zeroing, one launch ----
// seg0: 2560 rows x 128 uint4 (weights)  seg1: 4224 rows x 128 uint4 (XE)
// seg2: 61440 uint stores zeroing te-tails of QP/KP/VT
__global__ __launch_bounds__(256) void prep_all(const float* __restrict__ cq, const float* __restrict__ ck,
                                                const float* __restrict__ cv, const float* __restrict__ sw,
                                                const float* __restrict__ pw,
                                                const float* __restrict__ x, const float* __restrict__ meta,
                                                bf16* __restrict__ wqkvsx, bf16* __restrict__ wproj,
                                                bf16* __restrict__ xe,
                                                bf16* __restrict__ Qp, bf16* __restrict__ Kp,
                                                bf16* __restrict__ Vt) {
  int i = blockIdx.x * 256 + threadIdx.x;
  if (i < 327680) {                       // seg0: weights
    int row = i >> 7, v = i & 127;
    const float* src; bf16* dst;
    if (row < 512)       { src = cq + (size_t)row * 1024;          dst = wqkvsx + (size_t)row * 1024; }
    else if (row < 768)  { src = ck + (size_t)(row - 512) * 1024;  dst = wqkvsx + (size_t)row * 1024; }
    else if (row < 1024) { src = cv + (size_t)(row - 768) * 1024;  dst = wqkvsx + (size_t)row * 1024; }
    else if (row < 1536) { src = sw + (size_t)(row - 1024) * 1024; dst = wqkvsx + (size_t)row * 1024; }
    else                 { src = pw + (size_t)(row - 1536) * 1024; dst = wproj + (size_t)(row - 1536) * 1024; }
    float4 a0 = ((const float4*)src)[v * 2], a1 = ((const float4*)src)[v * 2 + 1];
    ((uint4*)dst)[v] = pack8(a0, a1);
  } else if (i < 868352) {                // seg1: x_ext
    int j = i - 327680;
    int r = j >> 7, v = j & 127;
    uint4 val = {0u, 0u, 0u, 0u};
    if (r < kMEXT) {
      int b = r / kTEXT, te = r - b * kTEXT;
      const float* src = (te < kNMETA) ? (meta + (size_t)te * kDIM)
                                       : (x + ((size_t)b * kT + (te - kNMETA)) * kDIM);
      float4 a0 = ((const float4*)src)[v * 2];
      float4 a1 = ((const float4*)src)[v * 2 + 1];
      val = pack8(a0, a1);
    }
    ((uint4*)(xe + (size_t)r * kDIM))[v] = val;
  } else {                                // seg2: zero pad tails (uint = 2 bf16)
    int j = i - 868352;
    if (j < 30720) {            // QP: (b*8+h) x 60 te x 32 uints
      int k = j & 31, te = (j >> 5) % 60, bh = j / (60 * 32);
      *(unsigned int*)(Qp + ((size_t)bh * kTP + 2052 + te) * 64 + k * 2) = 0u;
    } else if (j < 46080) {     // KP: (b*4+h) x 60 x 32
      int jj = j - 30720;
      int k = jj & 31, te = (jj >> 5) % 60, bh = jj / (60 * 32);
      *(unsigned int*)(Kp + ((size_t)bh * kTP + 2052 + te) * 64 + k * 2) = 0u;
    } else if (j < 61440) {     // VT: (b*4+kvh)*64+d rows, 30 uints each
      int jj = j - 46080;
      int k = jj % 30, rowd = jj / 30;    // 512 rows
      *(unsigned int*)(Vt + (size_t)rowd * kTP + 2052 + k * 2) = 0u;
    }
  }
}

// ========== 128x64-tile bf16 GEMM (K=1024, BK=32), global_load_lds staging ==========
// MODE 0: fused QKV+SX with norm/rope/pack epilogue:
//   tiles 0-7: Q head -> RMS+RoPE+gain -> QP ; 8-11: K -> RMS+RoPE -> KP ;
//   12-15: V -> transposed VT ; 16-23: SX (row remap, bf16).
// MODE 2: proj (f32 out).
template <int MODE>
__global__ __launch_bounds__(256) void gemm_t(const bf16* __restrict__ A,
                                              const bf16* __restrict__ W,
                                              void* __restrict__ O0, void* __restrict__ O1,
                                              void* __restrict__ O2, void* __restrict__ O3,
                                              const float* __restrict__ q_gain) {
  __shared__ short As[128 * 32];   // 8 KB
  __shared__ short Bs[64 * 32];    // 4 KB
  const int tid = threadIdx.x;
  const int wave = tid >> 6, lane = tid & 63;
  const int quad = lane >> 4, l16 = lane & 15;
  const int bm = blockIdx.y * 128, bn = blockIdx.x * 64;
  const int srow = tid >> 2, scol = (tid & 3) * 8;
  const bf16* ag0 = A + (size_t)(bm + srow) * 1024 + scol;
  const bf16* ag1 = A + (size_t)(bm + 64 + srow) * 1024 + scol;
  const bf16* bg0 = W + (size_t)(bn + srow) * 1024 + scol;
  char* asb = (char*)As + wave * 1024;
  char* bsb = (char*)Bs + wave * 1024;
  f32x4 acc[2][4] = {};
  for (int k0 = 0; k0 < 1024; k0 += 32) {
    __syncthreads();
    GLD_LDS16(ag0, asb);
    GLD_LDS16(ag1, asb + 4096);
    GLD_LDS16(bg0, bsb);
    ag0 += 32; ag1 += 32; bg0 += 32;
    __syncthreads();
    short8 af[2], bfr[4];
#pragma unroll
    for (int mi = 0; mi < 2; ++mi)
      af[mi] = *(const short8*)((const char*)As + (size_t)(wave * 32 + mi * 16 + l16) * 64 + quad * 16);
#pragma unroll
    for (int ni = 0; ni < 4; ++ni)
      bfr[ni] = *(const short8*)((const char*)Bs + (size_t)(ni * 16 + l16) * 64 + quad * 16);
#pragma unroll
    for (int mi = 0; mi < 2; ++mi)
#pragma unroll
      for (int ni = 0; ni < 4; ++ni)
        acc[mi][ni] = __builtin_amdgcn_mfma_f32_16x16x32_bf16(af[mi], bfr[ni], acc[mi][ni], 0, 0, 0);
  }
  // ---- epilogue ----
  if constexpr (MODE == 2) {
#pragma unroll
    for (int mi = 0; mi < 2; ++mi)
#pragma unroll
      for (int ni = 0; ni < 4; ++ni) {
        int colg = bn + ni * 16 + l16;
#pragma unroll
        for (int r = 0; r < 4; ++r) {
          int row = bm + wave * 32 + mi * 16 + quad * 4 + r;
          ((float*)O0)[(size_t)row * 1024 + colg] = acc[mi][ni][r];
        }
      }
  } else {
    const int tile = blockIdx.x;
    if (tile < 16) {
      float gain = (tile < 8) ? q_gain[tile] * 0.125f : 1.f;
      float inv0 = exp2f(-13.287712379549449f * (float)l16 * (1.f / 32.f));
      float inv1 = exp2f(-13.287712379549449f * (float)(l16 + 16) * (1.f / 32.f));
#pragma unroll
      for (int mi = 0; mi < 2; ++mi) {
        int row0 = bm + wave * 32 + mi * 16 + quad * 4;
        if (row0 >= kMEXT) continue;          // zero-pad input rows (4-row group fully pad)
        int b = row0 >= kTEXT ? 1 : 0;
        int te0 = row0 - b * kTEXT;
        if (tile < 12) {
          // RMS across the head's 64 dims (16-lane x 4-ni per row)
          float ss[4];
#pragma unroll
          for (int r = 0; r < 4; ++r) {
            float s = 0.f;
#pragma unroll
            for (int ni = 0; ni < 4; ++ni) s += acc[mi][ni][r] * acc[mi][ni][r];
#pragma unroll
            for (int off = 1; off < 16; off <<= 1) s += __shfl_xor(s, off, 64);
            ss[r] = s;
          }
          bf16* base = (tile < 8)
            ? (bf16*)O0 + (((size_t)(b * 8 + tile)) * kTP + te0) * 64 + l16
            : (bf16*)O1 + (((size_t)(b * 4 + tile - 8)) * kTP + te0) * 64 + l16;
#pragma unroll
          for (int r = 0; r < 4; ++r) {
            float rn = rsqrtf(ss[r] * (1.f / 64.f) + 1e-6f) * gain;  // gain commutes with rotation
            float te = (float)(te0 + r);
            float a0 = te * inv0, a1 = te * inv1;
            float c0 = __cosf(a0), s0 = __sinf(a0);
            float c1 = __cosf(a1), s1 = __sinf(a1);
            float v0 = acc[mi][0][r] * rn, v1 = acc[mi][1][r] * rn;
            float v2 = acc[mi][2][r] * rn, v3 = acc[mi][3][r] * rn;
            bf16* dst = base + (size_t)r * 64;
            dst[0]  = __float2bfloat16(v0 * c0 - v2 * s0);
            dst[16] = __float2bfloat16(v1 * c1 - v3 * s1);
            dst[32] = __float2bfloat16(v0 * s0 + v2 * c0);
            dst[48] = __float2bfloat16(v1 * s1 + v3 * c1);
          }
        } else {
          // V: transposed write Vt[(b*4+hv)*64+d][te], 4 consecutive te packed as 8B
          int hv = tile - 12;
#pragma unroll
          for (int ni = 0; ni < 4; ++ni) {
            union { unsigned long long q; bf16 hh[4]; } pw;
#pragma unroll
            for (int r = 0; r < 4; ++r) pw.hh[r] = __float2bfloat16(acc[mi][ni][r]);
            *(unsigned long long*)((bf16*)O2 +
                (((size_t)(b * 4 + hv)) * 64 + ni * 16 + l16) * kTP + te0) = pw.q;
          }
        }
      }
    } else {
      // SX scatter with row remap
#pragma unroll
      for (int mi = 0; mi < 2; ++mi)
#pragma unroll
        for (int ni = 0; ni < 4; ++ni) {
          int colg = bn - 1024 + ni * 16 + l16;
#pragma unroll
          for (int r = 0; r < 4; ++r) {
            int row = bm + wave * 32 + mi * 16 + quad * 4 + r;
            if (row < kMEXT) {
              int bb = row >= kTEXT ? 1 : 0;
              int te = row - bb * kTEXT;
              if (te >= kNMETA)
                ((bf16*)O3)[((size_t)(bb * kT + te - kNMETA)) * 512 + colg] =
                    __float2bfloat16(acc[mi][ni][r]);
            }
          }
        }
    }
  }
}

// ------- MFMA flash attention, kv-split x2: partial O (unscaled) + l to f32 buffers -------
__global__ __launch_bounds__(256) void attn_part(const bf16* __restrict__ Qp,
                                                 const bf16* __restrict__ Kp,
                                                 const bf16* __restrict__ Vt,
                                                 float* __restrict__ AO, float* __restrict__ AL) {
  __shared__ short Ks[64][72];
  __shared__ short Vs[64][72];
  __shared__ short Ps[4][16][72];
  const int part = blockIdx.x & 1;
  const int qt = (kQT - 1) - (blockIdx.x >> 1);   // longest first
  const int h = blockIdx.y, b = blockIdx.z;
  const int kvh = h >> 1;
  const int tid = threadIdx.x, wave = tid >> 6, lane = tid & 63;
  const int quad = lane >> 4, l16 = lane & 15;
  const int hsplit = (qt + 2) >> 1;
  const int kt_begin = part == 0 ? 0 : hsplit;
  const int kt_end = part == 0 ? hsplit : qt + 1;   // exclusive

  short8 qf[2];
  {
    const bf16* qrow = Qp + (((size_t)(b * 8 + h)) * kTP + qt * 64 + wave * 16 + l16) * 64 + quad * 8;
    qf[0] = *(const short8*)(qrow);
    qf[1] = *(const short8*)(qrow + 32);
  }
  short8 ones;
#pragma unroll
  for (int i = 0; i < 8; ++i) ones[i] = (short)0x3F80;   // bf16 1.0

  const bf16* kbase = Kp + ((size_t)(b * 4 + kvh)) * kTP * 64;
  const bf16* vbase = Vt + ((size_t)(b * 4 + kvh)) * 64 * kTP;

  const int r0row = tid >> 3, r0c8 = tid & 7;
  const int r1row = (256 + tid) >> 3, r1c8 = tid & 7;

  f32x4 O[4] = {};
  f32x4 lacc = {};
  const int q_abs = qt * 64 + wave * 16 + l16;

  uint4 kr0 = *(const uint4*)(kbase + (size_t)(kt_begin * 64 + r0row) * 64 + r0c8 * 8);
  uint4 kr1 = *(const uint4*)(kbase + (size_t)(kt_begin * 64 + r1row) * 64 + r1c8 * 8);
  uint4 vr0 = *(const uint4*)(vbase + (size_t)r0row * kTP + kt_begin * 64 + r0c8 * 8);
  uint4 vr1 = *(const uint4*)(vbase + (size_t)r1row * kTP + kt_begin * 64 + r1c8 * 8);

  for (int kt = kt_begin; kt < kt_end; ++kt) {
    __syncthreads();
    *(uint4*)&Ks[r0row][r0c8 * 8] = kr0;
    *(uint4*)&Ks[r1row][r1c8 * 8] = kr1;
    *(uint4*)&Vs[r0row][r0c8 * 8] = vr0;
    *(uint4*)&Vs[r1row][r1c8 * 8] = vr1;
    if (kt + 1 < kt_end) {
      int kn = (kt + 1) * 64;
      kr0 = *(const uint4*)(kbase + (size_t)(kn + r0row) * 64 + r0c8 * 8);
      kr1 = *(const uint4*)(kbase + (size_t)(kn + r1row) * 64 + r1c8 * 8);
      vr0 = *(const uint4*)(vbase + (size_t)r0row * kTP + kn + r0c8 * 8);
      vr1 = *(const uint4*)(vbase + (size_t)r1row * kTP + kn + r1c8 * 8);
    }
    __syncthreads();

    f32x4 st[4] = {};
#pragma unroll
    for (int nb = 0; nb < 4; ++nb) {
      short8 ak0 = *(const short8*)&Ks[nb * 16 + l16][quad * 8];
      st[nb] = __builtin_amdgcn_mfma_f32_16x16x32_bf16(ak0, qf[0], st[nb], 0, 0, 0);
      short8 ak1 = *(const short8*)&Ks[nb * 16 + l16][32 + quad * 8];
      st[nb] = __builtin_amdgcn_mfma_f32_16x16x32_bf16(ak1, qf[1], st[nb], 0, 0, 0);
    }
    if (kt == qt) {
      int key0 = kt * 64 + quad * 4;
#pragma unroll
      for (int nb = 0; nb < 4; ++nb)
#pragma unroll
        for (int rg = 0; rg < 4; ++rg)
          if (key0 + nb * 16 + rg > q_abs) st[nb][rg] = -1e30f;
    }
#pragma unroll
    for (int nb = 0; nb < 4; ++nb) {
      union { unsigned long long q; bf16 hh[4]; } pw;
#pragma unroll
      for (int rg = 0; rg < 4; ++rg) pw.hh[rg] = __float2bfloat16(__expf(st[nb][rg]));
      *(unsigned long long*)&Ps[wave][l16][nb * 16 + quad * 4] = pw.q;
    }
    short8 pf0 = *(const short8*)&Ps[wave][l16][quad * 8];
    short8 pf1 = *(const short8*)&Ps[wave][l16][32 + quad * 8];
    lacc = __builtin_amdgcn_mfma_f32_16x16x32_bf16(pf0, ones, lacc, 0, 0, 0);
    lacc = __builtin_amdgcn_mfma_f32_16x16x32_bf16(pf1, ones, lacc, 0, 0, 0);
#pragma unroll
    for (int db = 0; db < 4; ++db) {
      short8 bv0 = *(const short8*)&Vs[db * 16 + l16][quad * 8];
      O[db] = __builtin_amdgcn_mfma_f32_16x16x32_bf16(pf0, bv0, O[db], 0, 0, 0);
      short8 bv1 = *(const short8*)&Vs[db * 16 + l16][32 + quad * 8];
      O[db] = __builtin_amdgcn_mfma_f32_16x16x32_bf16(pf1, bv1, O[db], 0, 0, 0);
    }
  }
  size_t hb = (((size_t)part * 2 + b) * 8 + h);
  float* aoB = AO + hb * kTP * 64;
  float* alB = AL + hb * kTP;
#pragma unroll
  for (int rg = 0; rg < 4; ++rg) {
    int q = qt * 64 + wave * 16 + quad * 4 + rg;
    float* dst = aoB + (size_t)q * 64 + l16;
#pragma unroll
    for (int db = 0; db < 4; ++db) dst[db * 16] = O[db][rg];
    if (l16 == 0) alB[q] = lacc[rg];
  }
}

// ---------------- SSM prep via MFMA: per head h, [64 bt rows] x [48 = dt|B|C] ----------------
__global__ __launch_bounds__(256) void ssm_prep(const bf16* __restrict__ sx,
                                                const float* __restrict__ dtw, const float* __restrict__ dtb,
                                                const float* __restrict__ Bw, const float* __restrict__ Cw,
                                                const float* __restrict__ logA,
                                                float* __restrict__ LU, float* __restrict__ Cc) {
  __shared__ short Xs[64][72];
  __shared__ short Ws[48][72];
  const int bm = blockIdx.x * 64, h = blockIdx.y;
  const int tid = threadIdx.x, wave = tid >> 6, lane = tid & 63;
  const int quad = lane >> 4, l16 = lane & 15;
#pragma unroll
  for (int is = 0; is < 2; ++is) {
    int e = is * 256 + tid;
    int row = e >> 3, v = e & 7;
    uint4 val = *(const uint4*)(sx + ((size_t)(bm + row)) * 512 + h * 64 + v * 8);
    *(uint4*)&Xs[row][v * 8] = val;
  }
#pragma unroll
  for (int is = 0; is < 2; ++is) {
    int s = is * 256 + tid;
    if (s < 384) {
      int row = s >> 3, v = s & 7;
      const float* src = (row < 16) ? dtw + ((size_t)(h * 16 + row)) * 64
                       : (row < 32) ? Bw + ((size_t)(h * 16 + row - 16)) * 64
                                    : Cw + ((size_t)(h * 16 + row - 32)) * 64;
      float4 a0 = ((const float4*)src)[v * 2];
      float4 a1 = ((const float4*)src)[v * 2 + 1];
      *(uint4*)&Ws[row][v * 8] = pack8(a0, a1);
    }
  }
  __syncthreads();
  short8 af0 = *(const short8*)&Xs[wave * 16 + l16][quad * 8];
  short8 af1 = *(const short8*)&Xs[wave * 16 + l16][32 + quad * 8];
  f32x4 acc[3] = {};
#pragma unroll
  for (int nb = 0; nb < 3; ++nb) {
    short8 b0 = *(const short8*)&Ws[nb * 16 + l16][quad * 8];
    acc[nb] = __builtin_amdgcn_mfma_f32_16x16x32_bf16(af0, b0, acc[nb], 0, 0, 0);
    short8 b1 = *(const short8*)&Ws[nb * 16 + l16][32 + quad * 8];
    acc[nb] = __builtin_amdgcn_mfma_f32_16x16x32_bf16(af1, b1, acc[nb], 0, 0, 0);
  }
  float dtb_v = dtb[h * 16 + l16];
  float A_v = fminf(-expf(logA[h * 16 + l16]), 10.f);
#pragma unroll
  for (int rg = 0; rg < 4; ++rg) {
    int bt = bm + wave * 16 + quad * 4 + rg;
    size_t ix = (size_t)bt * 128 + h * 16 + l16;
    float raw = acc[0][rg] + dtb_v;
    float sp = fmaxf(raw, 0.f) + log1pf(expf(-fabsf(raw)));   // stable softplus
    float dt = fminf(sp, 1.f);
    float lav = fminf(fmaxf(dt * A_v, -0.5f), 0.f);
    *(float2*)(LU + 2 * ix) = make_float2(lav, acc[1][rg] * dt);
    Cc[ix] = acc[2][rg];
  }
}

// phase 1: 32-step sub-chunks; chain summaries written TRANSPOSED (b, hs, c)
__global__ __launch_bounds__(256) void ssm_scan1(const float* __restrict__ LU,
                                                 bf16* __restrict__ hloc, bf16* __restrict__ Pb,
                                                 float* __restrict__ chHt, float* __restrict__ chPt) {
  int id = blockIdx.x * 256 + threadIdx.x;   // b*8192 + c*128 + hs, c in [0,64)
  if (id >= 16384) return;
  int hs = id & 127, c = (id >> 7) & 63, b = id >> 13;
  float hv = 0.f, cum = 0.f;
  size_t base = ((size_t)b * kT) * 128 + hs;
  const float2* LU2 = (const float2*)LU;
  for (int i = 0; i < 32; ++i) {
    size_t ix = base + (size_t)(c * 32 + i) * 128;
    float2 lu = LU2[ix];
    cum += lu.x;
    hv = expf(lu.x) * hv + lu.y;
    hloc[ix] = __float2bfloat16(hv);
    Pb[ix] = __float2bfloat16(expf(fmaxf(cum, -30.f)));
  }
  int t = b * 8192 + hs * 64 + c;
  chHt[t] = hv;
  chPt[t] = expf(fmaxf(cum, -30.f));
}

// phase 2: 64-lane Hillis-Steele composition scan per chain; h0 (exclusive) in (b,c,hs) layout
__global__ __launch_bounds__(256) void ssm_scan2(const float* __restrict__ chHt,
                                                 const float* __restrict__ chPt,
                                                 float* __restrict__ h0) {
  int id = blockIdx.x * 256 + threadIdx.x;
  int c = id & 63;
  int chain = id >> 6;        // b*128 + hs
  int b = chain >> 7, hs = chain & 127;
  int t = b * 8192 + hs * 64 + c;
  float H = chHt[t], P = chPt[t];
#pragma unroll
  for (int off = 1; off < 64; off <<= 1) {
    float Hp = __shfl_up(H, off, 64);
    float Pp = __shfl_up(P, off, 64);
    if (c >= off) { H = H + P * Hp; P = P * Pp; }
  }
  float Hex = __shfl_up(H, 1, 64);
  if (c == 0) Hex = 0.f;
  h0[b * 8192 + c * 128 + hs] = Hex;
}

// ------- fused: attn kv-split combine (blocks 0..527) + ssm_out (blocks 528..1039) -------
__global__ __launch_bounds__(256) void combine_out(const float* __restrict__ AO,
                                                   const float* __restrict__ AL,
                                                   const float* __restrict__ attn_scale,
                                                   const bf16* __restrict__ hloc, const bf16* __restrict__ Pb,
                                                   const float* __restrict__ h0, const float* __restrict__ Cc,
                                                   const bf16* __restrict__ sx, const float* __restrict__ Ow,
                                                   const float* __restrict__ ssm_scale,
                                                   bf16* __restrict__ Y) {
  if (blockIdx.x < 528) {
    int id = blockIdx.x * 256 + threadIdx.x;     // 2*8*2112*4
    int d16 = id & 3;
    int tmp = id >> 2;
    int q = tmp % kTP; tmp /= kTP;
    int h = tmp & 7, b = tmp >> 3;
    if (q < kNMETA || q >= kTEXT) return;
    size_t hb0 = ((size_t)b * 8 + h), hb1 = ((size_t)(2 + b) * 8 + h);
    float l = AL[hb0 * kTP + q] + AL[hb1 * kTP + q];
    float so = attn_scale[0] / fmaxf(l, 1e-30f);
    const float4* p0 = (const float4*)(AO + (hb0 * kTP + q) * 64 + d16 * 16);
    const float4* p1 = (const float4*)(AO + (hb1 * kTP + q) * 64 + d16 * 16);
    bf16* dst = Y + ((size_t)(b * kT + q - kNMETA)) * kDIM + h * 64 + d16 * 16;
#pragma unroll
    for (int i = 0; i < 4; ++i) {
      float4 a = p0[i], c = p1[i];
      dst[i * 4 + 0] = __float2bfloat16((a.x + c.x) * so);
      dst[i * 4 + 1] = __float2bfloat16((a.y + c.y) * so);
      dst[i * 4 + 2] = __float2bfloat16((a.z + c.z) * so);
      dst[i * 4 + 3] = __float2bfloat16((a.w + c.w) * so);
    }
  } else {
    int id = (blockIdx.x - 528) * 256 + threadIdx.x;   // kMX*32
    int d4 = id & 3, h = (id >> 2) & 7, t = (id >> 5) & 2047, b = id >> 16;
    size_t ix0 = ((size_t)(b * kT + t)) * 128 + h * 16;
    int h0b = b * 8192 + (t >> 5) * 128 + h * 16;
    float hv[16], y = 0.f;
#pragma unroll
    for (int s = 0; s < 16; ++s) {
      float v = __bfloat162float(hloc[ix0 + s]) + __bfloat162float(Pb[ix0 + s]) * h0[h0b + s];
      hv[s] = v;
      y += Cc[ix0 + s] * v;
    }
    float x0 = __bfloat162float(sx[((size_t)(b * kT + t)) * 512 + h * 64]);
    float scl = ssm_scale[0];
    const float* ow = Ow + ((size_t)h * 64 + d4 * 16) * 16;
    bf16* dst = Y + ((size_t)(b * kT + t)) * kDIM + 512 + h * 64 + d4 * 16;
    float yx = y * x0;
#pragma unroll
    for (int d = 0; d < 16; ++d) {
      float acc = yx;
      const float* owr = ow + d * 16;
#pragma unroll
      for (int s = 0; s < 16; ++s) acc += hv[s] * owr[s];
      dst[d] = __float2bfloat16(acc * scl);
    }
  }
}

// ---------------- host ----------------
extern "C" void kernel_launch(void* const* d_in, const int* in_sizes, int n_in,
                              void* d_out, int out_size, void* d_ws, size_t ws_size,
                              hipStream_t stream) {
  (void)in_sizes; (void)n_in; (void)out_size; (void)ws_size;
  const float* x        = (const float*)d_in[0];
  const float* meta     = (const float*)d_in[1];
  const float* c_q_w    = (const float*)d_in[2];
  const float* c_k_w    = (const float*)d_in[3];
  const float* c_v_w    = (const float*)d_in[4];
  const float* q_gain   = (const float*)d_in[5];
  const float* ssm_in_w = (const float*)d_in[6];
  const float* proj_w   = (const float*)d_in[7];
  const float* attn_sc  = (const float*)d_in[8];
  const float* ssm_sc   = (const float*)d_in[9];
  const float* ssm_logA = (const float*)d_in[10];
  const float* ssm_Bw   = (const float*)d_in[11];
  const float* ssm_Cw   = (const float*)d_in[12];
  const float* ssm_dtw  = (const float*)d_in[13];
  const float* ssm_dtb  = (const float*)d_in[14];
  const float* ssm_Ow   = (const float*)d_in[15];

  char* w = (char*)d_ws;
  bf16*  XE = (bf16*)(w + oXE);
  bf16*  SX = (bf16*)(w + oSX);
  bf16*  YB = (bf16*)(w + oYB);
  bf16*  QP = (bf16*)(w + oQP);
  bf16*  KP = (bf16*)(w + oKP);
  bf16*  VT = (bf16*)(w + oVT);
  bf16*  WQ = (bf16*)(w + oWQ);
  bf16*  WP = (bf16*)(w + oWP);
  float* LU = (float*)(w + oLU);
  float* CC = (float*)(w + oCC);
  bf16*  HL = (bf16*)(w + oHL);
  bf16*  PB = (bf16*)(w + oPB);
  float* CH = (float*)(w + oCH);
  float* CP = (float*)(w + oCP);
  float* H0 = (float*)(w + oH0);
  float* AO = (float*)(w + oAO);
  float* AL = (float*)(w + oAL);

  prep_all<<<3632, 256, 0, stream>>>(c_q_w, c_k_w, c_v_w, ssm_in_w, proj_w,
                                     x, meta, WQ, WP, XE, QP, KP, VT);

  // QKV+SX fused GEMM with norm/rope/pack/transpose epilogue
  gemm_t<0><<<dim3(24, kMPAD / 128), 256, 0, stream>>>(XE, WQ, QP, KP, VT, SX, q_gain);

  attn_part<<<dim3(kQT * 2, 8, kB), 256, 0, stream>>>(QP, KP, VT, AO, AL);

  ssm_prep<<<dim3(kMX / 64, 8), 256, 0, stream>>>(SX, ssm_dtw, ssm_dtb, ssm_Bw, ssm_Cw,
                                                  ssm_logA, LU, CC);
  ssm_scan1<<<64, 256, 0, stream>>>(LU, HL, PB, CH, CP);
  ssm_scan2<<<64, 256, 0, stream>>>(CH, CP, H0);

  combine_out<<<1040, 256, 0, stream>>>(AO, AL, attn_sc, HL, PB, H0, CC, SX, ssm_Ow, ssm_sc, YB);

  gemm_t<2><<<dim3(16, kMX / 128), 256, 0, stream>>>(YB, WP, d_out, nullptr, nullptr, nullptr, nullptr);
}